// Round 1
// baseline (9084.525 us; speedup 1.0000x reference)
//
#include <hip/hip_runtime.h>
#include <hip/hip_bf16.h>

#define NN 50000
#define FIN 256
#define F1 256      // HEADS*HID
#define HEADS 4
#define HID 64
#define NC 40
#define NE 1600000
#define SLOPE 0.2f

typedef unsigned int u32;
typedef unsigned short u16;

__device__ __forceinline__ float us2f(u32 u){ u32 b = u << 16; return __uint_as_float(b); }
__device__ __forceinline__ float ldf(const void* p, int i, int isF){
  return isF ? ((const float*)p)[i] : us2f(((const u16*)p)[i]);
}
__device__ __forceinline__ u16 f2bf(float f){
  u32 b = __float_as_uint(f);
  u32 r = (b + 0x7fffu + ((b >> 16) & 1u)) >> 16;
  return (u16)r;
}
__device__ __forceinline__ int ld_src(const int* ei, int i, int i64){ return i64 ? ei[2*i] : ei[i]; }
__device__ __forceinline__ int ld_dst(const int* ei, int i, int i64){ return i64 ? ei[2*(NE+i)] : ei[NE+i]; }

// ---- dtype world detection: flags[0]=1 if floats are f32, flags[1]=1 if ints are int64
__global__ void k_detect(const u32* xw, const int* ei, int* flags){
  __shared__ int cq, ci;
  if(threadIdx.x==0){ cq=0; ci=0; }
  __syncthreads();
  u32 w = xw[threadIdx.x];
  int q = (w >> 7) & 0xff;              // bf16-exponent field if data is bf16 pairs
  if(q >= 90 && q <= 160) atomicAdd(&cq, 1);
  if(ei[2*threadIdx.x+1] != 0) atomicAdd(&ci, 1);
  __syncthreads();
  if(threadIdx.x==0){
    flags[0] = (cq <= 128) ? 1 : 0;     // bf16 data -> ~255 hits; f32 -> ~71
    flags[1] = (ci == 0) ? 1 : 0;       // int64: all odd int32 words are zero
  }
}

// ---- CSR build
__global__ void k_count(const int* __restrict__ ei, const int* __restrict__ flags, int* __restrict__ deg){
  int i64 = flags[1];
  int i = blockIdx.x*256 + threadIdx.x;
  if(i < NE) atomicAdd(&deg[ld_dst(ei,i,i64)], 1);
}

__global__ __launch_bounds__(1024) void k_scan(int* __restrict__ degfill, int* __restrict__ rowptr){
  __shared__ int sums[1024];
  int t = threadIdx.x;
  const int C = (NN + 1023) / 1024;
  int base = t * C, s = 0;
  for(int j=0;j<C;j++){ int idx=base+j; if(idx<NN) s += degfill[idx]; }
  sums[t] = s; __syncthreads();
  for(int off=1; off<1024; off<<=1){
    int v = (t >= off) ? sums[t-off] : 0;
    __syncthreads();
    sums[t] += v;
    __syncthreads();
  }
  int run = (t==0) ? 0 : sums[t-1];
  for(int j=0;j<C;j++){
    int idx = base + j;
    if(idx < NN){ int d = degfill[idx]; rowptr[idx] = run; degfill[idx] = run; run += d; }
  }
  if(t==1023) rowptr[NN] = run;
}

__global__ void k_fill(const int* __restrict__ ei, const int* __restrict__ flags,
                       int* __restrict__ fill, int* __restrict__ adj){
  int i64 = flags[1];
  int i = blockIdx.x*256 + threadIdx.x;
  if(i < NE){
    int d = ld_dst(ei,i,i64);
    int p = atomicAdd(&fill[d], 1);
    adj[p] = ld_src(ei,i,i64);
  }
}

// ---- GEMM1: h1[N,256] = x[N,256] @ W1[256,256], f32 accum
__global__ __launch_bounds__(256) void k_gemm1(const void* __restrict__ x, const void* __restrict__ W,
                                               const int* __restrict__ flags, float* __restrict__ h1){
  int isF = flags[0];
  __shared__ float xs[64][32];          // [kk][r]
  int r0 = blockIdx.x * 32;
  int c = threadIdx.x;                  // output column 0..255
  float acc[32];
  #pragma unroll
  for(int r=0;r<32;r++) acc[r] = 0.f;
  int lr = threadIdx.x >> 3;            // 0..31 row
  int lk = (threadIdx.x & 7) * 8;       // 0..56 k-offset
  for(int k0=0; k0<FIN; k0+=64){
    float xv[8];
    int row = r0 + lr;
    if(row < NN){
      if(isF){
        const float* fp = (const float*)x + (size_t)row*FIN + k0 + lk;
        float4 a = *(const float4*)fp, b = *(const float4*)(fp+4);
        xv[0]=a.x; xv[1]=a.y; xv[2]=a.z; xv[3]=a.w; xv[4]=b.x; xv[5]=b.y; xv[6]=b.z; xv[7]=b.w;
      } else {
        const u16* up = (const u16*)x + (size_t)row*FIN + k0 + lk;
        uint4 a = *(const uint4*)up;
        xv[0]=us2f(a.x&0xffff); xv[1]=us2f(a.x>>16);
        xv[2]=us2f(a.y&0xffff); xv[3]=us2f(a.y>>16);
        xv[4]=us2f(a.z&0xffff); xv[5]=us2f(a.z>>16);
        xv[6]=us2f(a.w&0xffff); xv[7]=us2f(a.w>>16);
      }
    } else {
      #pragma unroll
      for(int j=0;j<8;j++) xv[j] = 0.f;
    }
    __syncthreads();
    #pragma unroll
    for(int j=0;j<8;j++) xs[lk+j][lr] = xv[j];
    __syncthreads();
    #pragma unroll
    for(int kk=0; kk<64; kk++){
      float wv = ldf(W, (k0+kk)*F1 + c, isF);
      #pragma unroll
      for(int rg=0; rg<8; rg++){
        float4 v = *(const float4*)&xs[kk][rg*4];
        acc[rg*4+0] += v.x*wv; acc[rg*4+1] += v.y*wv;
        acc[rg*4+2] += v.z*wv; acc[rg*4+3] += v.w*wv;
      }
    }
  }
  #pragma unroll
  for(int r=0;r<32;r++){
    int row = r0 + r;
    if(row < NN) h1[(size_t)row*F1 + c] = acc[r];
  }
}

// ---- attention coefficients layer 1: a_src/a_dst [N,4]
__global__ __launch_bounds__(256) void k_att1(const float* __restrict__ h1, const void* __restrict__ as,
                                              const void* __restrict__ ad, const int* __restrict__ flags,
                                              float* __restrict__ aS, float* __restrict__ aD){
  int isF = flags[0];
  int lane = threadIdx.x & 63;
  int node = blockIdx.x*4 + (threadIdx.x >> 6);
  float4 hv = *(const float4*)&h1[(size_t)node*F1 + lane*4];
  int h = lane >> 4;
  int ci = (lane & 15) * 4;
  float s0=ldf(as,h*HID+ci+0,isF), s1=ldf(as,h*HID+ci+1,isF), s2=ldf(as,h*HID+ci+2,isF), s3=ldf(as,h*HID+ci+3,isF);
  float d0=ldf(ad,h*HID+ci+0,isF), d1=ldf(ad,h*HID+ci+1,isF), d2=ldf(ad,h*HID+ci+2,isF), d3=ldf(ad,h*HID+ci+3,isF);
  float ps = hv.x*s0 + hv.y*s1 + hv.z*s2 + hv.w*s3;
  float pd = hv.x*d0 + hv.y*d1 + hv.z*d2 + hv.w*d3;
  #pragma unroll
  for(int off=1; off<16; off<<=1){ ps += __shfl_xor(ps,off,64); pd += __shfl_xor(pd,off,64); }
  if((lane & 15) == 0){ aS[node*HEADS + h] = ps; aD[node*HEADS + h] = pd; }
}

// ---- layer-1 aggregation + bias + BN + ELU -> h2 (one wave per node)
__global__ __launch_bounds__(256) void k_agg1(const float* __restrict__ h1,
  const float* __restrict__ aS, const float* __restrict__ aD,
  const int* __restrict__ rowptr, const int* __restrict__ adj,
  const void* __restrict__ b1, const void* __restrict__ g1, const void* __restrict__ be1,
  const void* __restrict__ mn1, const void* __restrict__ vr1,
  const int* __restrict__ flags, float* __restrict__ h2){
  int isF = flags[0];
  int lane = threadIdx.x & 63;
  int node = blockIdx.x*4 + (threadIdx.x >> 6);
  int h = lane >> 4;
  int beg = rowptr[node], end = rowptr[node+1];
  float4 ad4 = *(const float4*)&aD[node*HEADS];
  float adh[4] = {ad4.x, ad4.y, ad4.z, ad4.w};
  float m[4] = {-1e30f,-1e30f,-1e30f,-1e30f}, sden[4] = {0.f,0.f,0.f,0.f};
  for(int e=beg+lane; e<end; e+=64){
    int src = adj[e];
    float4 as4 = *(const float4*)&aS[src*HEADS];
    float ev[4] = {as4.x+adh[0], as4.y+adh[1], as4.z+adh[2], as4.w+adh[3]};
    #pragma unroll
    for(int q=0;q<4;q++){
      float e2 = ev[q] > 0.f ? ev[q] : SLOPE*ev[q];
      if(e2 > m[q]){ sden[q] = sden[q]*__expf(m[q]-e2) + 1.f; m[q] = e2; }
      else sden[q] += __expf(e2 - m[q]);
    }
  }
  if(lane == 0){   // self loop
    float4 as4 = *(const float4*)&aS[node*HEADS];
    float ev[4] = {as4.x+adh[0], as4.y+adh[1], as4.z+adh[2], as4.w+adh[3]};
    #pragma unroll
    for(int q=0;q<4;q++){
      float e2 = ev[q] > 0.f ? ev[q] : SLOPE*ev[q];
      if(e2 > m[q]){ sden[q] = sden[q]*__expf(m[q]-e2) + 1.f; m[q] = e2; }
      else sden[q] += __expf(e2 - m[q]);
    }
  }
  #pragma unroll
  for(int off=1; off<64; off<<=1){
    #pragma unroll
    for(int q=0;q<4;q++){
      float m2 = __shfl_xor(m[q],off,64), s2 = __shfl_xor(sden[q],off,64);
      float M = fmaxf(m[q], m2);
      sden[q] = sden[q]*__expf(m[q]-M) + s2*__expf(m2-M);
      m[q] = M;
    }
  }
  float mh = m[h], inv = 1.f/(sden[h] + 1e-16f);
  float adhh = adh[h];
  float a0=0.f, a1=0.f, a2=0.f, a3=0.f;
  for(int e=beg; e<end; e++){
    int src = adj[e];                               // uniform -> broadcast
    float ev = aS[src*HEADS + h] + adhh;
    ev = ev > 0.f ? ev : SLOPE*ev;
    float al = __expf(ev - mh) * inv;
    float4 hv = *(const float4*)&h1[(size_t)src*F1 + lane*4];
    a0 += al*hv.x; a1 += al*hv.y; a2 += al*hv.z; a3 += al*hv.w;
  }
  { // self loop
    float ev = aS[node*HEADS + h] + adhh;
    ev = ev > 0.f ? ev : SLOPE*ev;
    float al = __expf(ev - mh) * inv;
    float4 hv = *(const float4*)&h1[(size_t)node*F1 + lane*4];
    a0 += al*hv.x; a1 += al*hv.y; a2 += al*hv.z; a3 += al*hv.w;
  }
  int c = lane*4;
  float o[4] = {a0,a1,a2,a3};
  #pragma unroll
  for(int j=0;j<4;j++){
    float v = o[j] + ldf(b1, c+j, isF);
    float mu = ldf(mn1,c+j,isF), va = ldf(vr1,c+j,isF);
    float gg = ldf(g1,c+j,isF),  bb = ldf(be1,c+j,isF);
    v = (v - mu) * rsqrtf(va + 1e-5f) * gg + bb;
    v = v > 0.f ? v : (__expf(v) - 1.f);            // ELU
    o[j] = v;
  }
  *(float4*)&h2[(size_t)node*F1 + lane*4] = make_float4(o[0],o[1],o[2],o[3]);
}

// ---- GEMM2 (wave per node) + attention coefficient dots layer 2
__global__ __launch_bounds__(256) void k_gemm2(const float* __restrict__ h2, const void* __restrict__ W2,
    const void* __restrict__ as2, const void* __restrict__ ad2, const int* __restrict__ flags,
    float* __restrict__ h2p, float* __restrict__ aS2, float* __restrict__ aD2){
  int isF = flags[0];
  __shared__ float w2s[F1*NC];          // 40 KB
  __shared__ float sh2[4][F1];          // 4 KB
  for(int i=threadIdx.x; i<F1*NC; i+=256) w2s[i] = ldf(W2, i, isF);
  int w = threadIdx.x >> 6, lane = threadIdx.x & 63;
  int node = blockIdx.x*4 + w;
  for(int i=lane; i<F1; i+=64) sh2[w][i] = h2[(size_t)node*F1 + i];
  __syncthreads();
  float acc = 0.f;
  if(lane < NC){
    #pragma unroll 8
    for(int k=0; k<F1; k++) acc += sh2[w][k] * w2s[k*NC + lane];
  }
  float av = (lane < NC) ? ldf(as2, lane, isF) : 0.f;
  float dv = (lane < NC) ? ldf(ad2, lane, isF) : 0.f;
  float ps = acc*av, pd = acc*dv;
  #pragma unroll
  for(int off=1; off<64; off<<=1){ ps += __shfl_xor(ps,off,64); pd += __shfl_xor(pd,off,64); }
  if(lane < NC) h2p[(size_t)node*NC + lane] = acc;
  if(lane == 0){ aS2[node] = ps; aD2[node] = pd; }
}

// ---- layer-2 aggregation -> output
__global__ __launch_bounds__(256) void k_agg2(const float* __restrict__ h2p,
  const float* __restrict__ aS2, const float* __restrict__ aD2,
  const int* __restrict__ rowptr, const int* __restrict__ adj,
  const void* __restrict__ b2, const int* __restrict__ flags, void* __restrict__ out){
  int isF = flags[0];
  int lane = threadIdx.x & 63;
  int node = blockIdx.x*4 + (threadIdx.x >> 6);
  int beg = rowptr[node], end = rowptr[node+1];
  float adv = aD2[node];
  float m = -1e30f, sden = 0.f;
  for(int e=beg+lane; e<end; e+=64){
    int src = adj[e];
    float ev = aS2[src] + adv; ev = ev > 0.f ? ev : SLOPE*ev;
    if(ev > m){ sden = sden*__expf(m-ev) + 1.f; m = ev; }
    else sden += __expf(ev - m);
  }
  if(lane == 0){
    float ev = aS2[node] + adv; ev = ev > 0.f ? ev : SLOPE*ev;
    if(ev > m){ sden = sden*__expf(m-ev) + 1.f; m = ev; }
    else sden += __expf(ev - m);
  }
  #pragma unroll
  for(int off=1; off<64; off<<=1){
    float m2 = __shfl_xor(m,off,64), s2 = __shfl_xor(sden,off,64);
    float M = fmaxf(m, m2);
    sden = sden*__expf(m-M) + s2*__expf(m2-M);
    m = M;
  }
  float inv = 1.f/(sden + 1e-16f);
  float acc = 0.f;
  for(int e=beg; e<end; e++){
    int src = adj[e];
    float ev = aS2[src] + adv; ev = ev > 0.f ? ev : SLOPE*ev;
    float al = __expf(ev - m) * inv;
    if(lane < NC) acc += al * h2p[(size_t)src*NC + lane];
  }
  {
    float ev = aS2[node] + adv; ev = ev > 0.f ? ev : SLOPE*ev;
    float al = __expf(ev - m) * inv;
    if(lane < NC) acc += al * h2p[(size_t)node*NC + lane];
  }
  if(lane < NC){
    float o = acc + ldf(b2, lane, isF);
    if(isF) ((float*)out)[(size_t)node*NC + lane] = o;
    else    ((u16*)out)[(size_t)node*NC + lane] = f2bf(o);
  }
}

extern "C" void kernel_launch(void* const* d_in, const int* in_sizes, int n_in,
                              void* d_out, int out_size, void* d_ws, size_t ws_size,
                              hipStream_t stream){
  (void)in_sizes; (void)n_in; (void)out_size; (void)ws_size;
  const void* x   = d_in[0];
  const int*  ei  = (const int*)d_in[1];
  const void* W1  = d_in[2];
  const void* as1 = d_in[3];
  const void* ad1 = d_in[4];
  const void* b1  = d_in[5];
  const void* g1  = d_in[6];
  const void* be1 = d_in[7];
  const void* mn1 = d_in[8];
  const void* vr1 = d_in[9];
  const void* W2  = d_in[10];
  const void* as2 = d_in[11];
  const void* ad2 = d_in[12];
  const void* b2  = d_in[13];

  char* ws = (char*)d_ws;
  float* h1    = (float*)(ws + 0);            // 51,200,000 B
  float* h2    = (float*)(ws + 51200000);     // 51,200,000 B
  float* h2p   = (float*)(ws + 102400000);    //  8,000,000 B
  float* aS1   = (float*)(ws + 110400000);    //    800,000 B
  float* aD1   = (float*)(ws + 111200000);    //    800,000 B
  float* aS2   = (float*)(ws + 112000000);    //    200,000 B
  float* aD2   = (float*)(ws + 112200000);    //    200,000 B
  int*  rowptr = (int*)  (ws + 112400000);    //    200,016 B
  int*  rowfill= (int*)  (ws + 112600016);    //    200,000 B (deg, then fill cursor)
  int*  adj    = (int*)  (ws + 112800016);    //  6,400,000 B
  int*  flags  = (int*)  (ws + 119200016);    //         16 B

  hipMemsetAsync(rowfill, 0, NN*sizeof(int), stream);
  k_detect<<<1, 256, 0, stream>>>((const u32*)x, ei, flags);
  k_count <<<(NE+255)/256, 256, 0, stream>>>(ei, flags, rowfill);
  k_scan  <<<1, 1024, 0, stream>>>(rowfill, rowptr);
  k_fill  <<<(NE+255)/256, 256, 0, stream>>>(ei, flags, rowfill, adj);
  k_gemm1 <<<(NN+31)/32, 256, 0, stream>>>(x, W1, flags, h1);
  k_att1  <<<NN/4, 256, 0, stream>>>(h1, as1, ad1, flags, aS1, aD1);
  k_agg1  <<<NN/4, 256, 0, stream>>>(h1, aS1, aD1, rowptr, adj, b1, g1, be1, mn1, vr1, flags, h2);
  k_gemm2 <<<NN/4, 256, 0, stream>>>(h2, W2, as2, ad2, flags, h2p, aS2, aD2);
  k_agg2  <<<NN/4, 256, 0, stream>>>(h2p, aS2, aD2, rowptr, adj, b2, flags, d_out);
}

// Round 3
// 1003.885 us; speedup vs baseline: 9.0494x; 9.0494x over previous
//
#include <hip/hip_runtime.h>
#include <hip/hip_bf16.h>

#define NN 50000
#define FIN 256
#define F1 256      // HEADS*HID
#define HEADS 4
#define HID 64
#define NC 40
#define NE 1600000
#define SLOPE 0.2f

typedef unsigned int u32;
typedef unsigned short u16;
typedef __attribute__((ext_vector_type(8))) short bf16x8;
typedef __attribute__((ext_vector_type(4))) float f32x4;

__device__ __forceinline__ float us2f(u32 u){ u32 b = u << 16; return __uint_as_float(b); }
__device__ __forceinline__ u16 f2bf(float f){
  u32 b = __float_as_uint(f);
  u32 r = (b + 0x7fffu + ((b >> 16) & 1u)) >> 16;
  return (u16)r;
}
__device__ __forceinline__ int ld_src(const int* ei, int i, int i64){ return i64 ? ei[2*i] : ei[i]; }
__device__ __forceinline__ int ld_dst(const int* ei, int i, int i64){ return i64 ? ei[2*(NE+i)] : ei[NE+i]; }

// ---- int-width detection: flags[1]=1 if edge_index is int64 on device
__global__ void k_detect(const int* ei, int* flags){
  __shared__ int ci;
  if(threadIdx.x==0) ci=0;
  __syncthreads();
  if(ei[2*threadIdx.x+1] != 0) atomicAdd(&ci, 1);
  __syncthreads();
  if(threadIdx.x==0){ flags[0] = 0; flags[1] = (ci == 0) ? 1 : 0; }
}

// ---- CSR build
__global__ void k_count(const int* __restrict__ ei, const int* __restrict__ flags, int* __restrict__ deg){
  int i64 = flags[1];
  int i = blockIdx.x*256 + threadIdx.x;
  if(i < NE) atomicAdd(&deg[ld_dst(ei,i,i64)], 1);
}

__global__ __launch_bounds__(1024) void k_scan(int* __restrict__ degfill, int* __restrict__ rowptr){
  __shared__ int sums[1024];
  int t = threadIdx.x;
  const int C = (NN + 1023) / 1024;
  int base = t * C, s = 0;
  for(int j=0;j<C;j++){ int idx=base+j; if(idx<NN) s += degfill[idx]; }
  sums[t] = s; __syncthreads();
  for(int off=1; off<1024; off<<=1){
    int v = (t >= off) ? sums[t-off] : 0;
    __syncthreads();
    sums[t] += v;
    __syncthreads();
  }
  int run = (t==0) ? 0 : sums[t-1];
  for(int j=0;j<C;j++){
    int idx = base + j;
    if(idx < NN){ int d = degfill[idx]; rowptr[idx] = run; degfill[idx] = run; run += d; }
  }
  if(t==1023) rowptr[NN] = run;
}

__global__ void k_fill(const int* __restrict__ ei, const int* __restrict__ flags,
                       int* __restrict__ fill, int* __restrict__ adj){
  int i64 = flags[1];
  int i = blockIdx.x*256 + threadIdx.x;
  if(i < NE){
    int d = ld_dst(ei,i,i64);
    int p = atomicAdd(&fill[d], 1);
    adj[p] = ld_src(ei,i,i64);
  }
}

// ---- split x (f32) -> xh + xl (bf16 each), xh+xl ~ x to ~16 mantissa bits
__global__ void k_splitx(const float* __restrict__ x, u16* __restrict__ xh, u16* __restrict__ xl){
  int i = (blockIdx.x*256 + threadIdx.x) * 8;
  float4 a = *(const float4*)(x+i);
  float4 b = *(const float4*)(x+i+4);
  float v[8] = {a.x,a.y,a.z,a.w,b.x,b.y,b.z,b.w};
  u16 hi[8], lo[8];
  #pragma unroll
  for(int j=0;j<8;j++){
    u16 h = f2bf(v[j]);
    hi[j] = h;
    lo[j] = f2bf(v[j] - us2f(h));
  }
  *(ushort4*)&xh[i]   = make_ushort4(hi[0],hi[1],hi[2],hi[3]);
  *(ushort4*)&xh[i+4] = make_ushort4(hi[4],hi[5],hi[6],hi[7]);
  *(ushort4*)&xl[i]   = make_ushort4(lo[0],lo[1],lo[2],lo[3]);
  *(ushort4*)&xl[i+4] = make_ushort4(lo[4],lo[5],lo[6],lo[7]);
}

// ---- transpose + split W1 (f32 [k][n]) -> W1t hi/lo (bf16 [n][k])
__global__ void k_tw1(const float* __restrict__ W1, u16* __restrict__ wh, u16* __restrict__ wl){
  int id = blockIdx.x*256 + threadIdx.x;    // 65536 total
  int n = id & 255, k = id >> 8;
  float v = W1[k*F1 + n];
  u16 h = f2bf(v);
  wh[n*FIN + k] = h;
  wl[n*FIN + k] = f2bf(v - us2f(h));
}

// ---- GEMM1 (MFMA bf16x3): h1[N,256](f32) = x[N,256] @ W1, ~f32 precision
// block = 256 thr (4 waves); block covers 64 rows; wave w: rows r0+w*16..+15, all 256 cols
__global__ __launch_bounds__(256) void k_gemm1(const short* __restrict__ xh, const short* __restrict__ xl,
                                               const short* __restrict__ wh, const short* __restrict__ wl,
                                               float* __restrict__ h1){
  int w = threadIdx.x >> 6, lane = threadIdx.x & 63;
  int lo = lane & 15, hi = lane >> 4;
  int rowbase = blockIdx.x*64 + w*16;
  int arow = rowbase + lo; if(arow >= NN) arow = NN-1;
  f32x4 acc[16];
  #pragma unroll
  for(int t=0;t<16;t++) acc[t] = (f32x4){0.f,0.f,0.f,0.f};
  const short* xph = xh + (size_t)arow*FIN + 8*hi;
  const short* xpl = xl + (size_t)arow*FIN + 8*hi;
  const short* wph = wh + (size_t)lo*FIN + 8*hi;
  const short* wpl = wl + (size_t)lo*FIN + 8*hi;
  for(int k0=0; k0<FIN; k0+=32){
    bf16x8 ah = *(const bf16x8*)(xph + k0);
    bf16x8 al = *(const bf16x8*)(xpl + k0);
    #pragma unroll
    for(int t=0;t<16;t++){
      bf16x8 bh = *(const bf16x8*)(wph + (size_t)t*16*FIN + k0);
      bf16x8 bl = *(const bf16x8*)(wpl + (size_t)t*16*FIN + k0);
      acc[t] = __builtin_amdgcn_mfma_f32_16x16x32_bf16(ah, bh, acc[t], 0, 0, 0);
      acc[t] = __builtin_amdgcn_mfma_f32_16x16x32_bf16(al, bh, acc[t], 0, 0, 0);
      acc[t] = __builtin_amdgcn_mfma_f32_16x16x32_bf16(ah, bl, acc[t], 0, 0, 0);
    }
  }
  #pragma unroll
  for(int t=0;t<16;t++){
    #pragma unroll
    for(int r=0;r<4;r++){
      int row = rowbase + hi*4 + r;
      if(row < NN) h1[(size_t)row*F1 + t*16 + lo] = acc[t][r];
    }
  }
}

// ---- attention coefficients layer 1: a_src/a_dst [N,4]
__global__ __launch_bounds__(256) void k_att1(const float* __restrict__ h1, const float* __restrict__ as,
                                              const float* __restrict__ ad,
                                              float* __restrict__ aS, float* __restrict__ aD){
  int lane = threadIdx.x & 63;
  int node = blockIdx.x*4 + (threadIdx.x >> 6);
  float4 hv = *(const float4*)&h1[(size_t)node*F1 + lane*4];
  int h = lane >> 4;
  int ci = (lane & 15) * 4;
  float s0=as[h*HID+ci+0], s1=as[h*HID+ci+1], s2=as[h*HID+ci+2], s3=as[h*HID+ci+3];
  float d0=ad[h*HID+ci+0], d1=ad[h*HID+ci+1], d2=ad[h*HID+ci+2], d3=ad[h*HID+ci+3];
  float ps = hv.x*s0 + hv.y*s1 + hv.z*s2 + hv.w*s3;
  float pd = hv.x*d0 + hv.y*d1 + hv.z*d2 + hv.w*d3;
  #pragma unroll
  for(int off=1; off<16; off<<=1){ ps += __shfl_xor(ps,off,64); pd += __shfl_xor(pd,off,64); }
  if((lane & 15) == 0){ aS[node*HEADS + h] = ps; aD[node*HEADS + h] = pd; }
}

// ---- layer-1 aggregation + bias + BN + ELU -> h2 (f32), one wave per node
__global__ __launch_bounds__(256) void k_agg1(const float* __restrict__ h1,
  const float* __restrict__ aS, const float* __restrict__ aD,
  const int* __restrict__ rowptr, const int* __restrict__ adj,
  const float* __restrict__ b1, const float* __restrict__ g1, const float* __restrict__ be1,
  const float* __restrict__ mn1, const float* __restrict__ vr1,
  float* __restrict__ h2){
  int lane = threadIdx.x & 63;
  int node = blockIdx.x*4 + (threadIdx.x >> 6);
  int h = lane >> 4;
  int beg = rowptr[node], end = rowptr[node+1];
  float4 ad4 = *(const float4*)&aD[node*HEADS];
  float adh[4] = {ad4.x, ad4.y, ad4.z, ad4.w};
  float m[4] = {-1e30f,-1e30f,-1e30f,-1e30f}, sden[4] = {0.f,0.f,0.f,0.f};
  for(int e=beg+lane; e<end; e+=64){
    int src = adj[e];
    float4 as4 = *(const float4*)&aS[src*HEADS];
    float ev[4] = {as4.x+adh[0], as4.y+adh[1], as4.z+adh[2], as4.w+adh[3]};
    #pragma unroll
    for(int q=0;q<4;q++){
      float e2 = ev[q] > 0.f ? ev[q] : SLOPE*ev[q];
      if(e2 > m[q]){ sden[q] = sden[q]*__expf(m[q]-e2) + 1.f; m[q] = e2; }
      else sden[q] += __expf(e2 - m[q]);
    }
  }
  if(lane == 0){   // self loop
    float4 as4 = *(const float4*)&aS[node*HEADS];
    float ev[4] = {as4.x+adh[0], as4.y+adh[1], as4.z+adh[2], as4.w+adh[3]};
    #pragma unroll
    for(int q=0;q<4;q++){
      float e2 = ev[q] > 0.f ? ev[q] : SLOPE*ev[q];
      if(e2 > m[q]){ sden[q] = sden[q]*__expf(m[q]-e2) + 1.f; m[q] = e2; }
      else sden[q] += __expf(e2 - m[q]);
    }
  }
  #pragma unroll
  for(int off=1; off<64; off<<=1){
    #pragma unroll
    for(int q=0;q<4;q++){
      float m2 = __shfl_xor(m[q],off,64), s2 = __shfl_xor(sden[q],off,64);
      float M = fmaxf(m[q], m2);
      sden[q] = sden[q]*__expf(m[q]-M) + s2*__expf(m2-M);
      m[q] = M;
    }
  }
  float mh = m[h], inv = 1.f/(sden[h] + 1e-16f);
  float adhh = adh[h];
  float a0=0.f, a1=0.f, a2=0.f, a3=0.f;
  for(int e=beg; e<end; e++){
    int src = adj[e];                               // uniform -> broadcast
    float ev = aS[src*HEADS + h] + adhh;
    ev = ev > 0.f ? ev : SLOPE*ev;
    float al = __expf(ev - mh) * inv;
    float4 hv = *(const float4*)&h1[(size_t)src*F1 + lane*4];
    a0 += al*hv.x; a1 += al*hv.y; a2 += al*hv.z; a3 += al*hv.w;
  }
  { // self loop
    float ev = aS[node*HEADS + h] + adhh;
    ev = ev > 0.f ? ev : SLOPE*ev;
    float al = __expf(ev - mh) * inv;
    float4 hv = *(const float4*)&h1[(size_t)node*F1 + lane*4];
    a0 += al*hv.x; a1 += al*hv.y; a2 += al*hv.z; a3 += al*hv.w;
  }
  int c = lane*4;
  float o[4] = {a0,a1,a2,a3};
  #pragma unroll
  for(int j=0;j<4;j++){
    float v = o[j] + b1[c+j];
    v = (v - mn1[c+j]) * rsqrtf(vr1[c+j] + 1e-5f) * g1[c+j] + be1[c+j];
    v = v > 0.f ? v : (__expf(v) - 1.f);            // ELU
    o[j] = v;
  }
  *(float4*)&h2[(size_t)node*F1 + c] = make_float4(o[0],o[1],o[2],o[3]);
}

// ---- GEMM2 (wave per node) + attention coefficient dots layer 2
__global__ __launch_bounds__(256) void k_gemm2(const float* __restrict__ h2, const float* __restrict__ W2,
    const float* __restrict__ as2, const float* __restrict__ ad2,
    float* __restrict__ h2p, float* __restrict__ aS2, float* __restrict__ aD2){
  __shared__ float w2s[F1*NC];          // 40 KB
  __shared__ float sh2[4][F1];          // 4 KB
  for(int i=threadIdx.x; i<F1*NC; i+=256) w2s[i] = W2[i];
  int w = threadIdx.x >> 6, lane = threadIdx.x & 63;
  int node = blockIdx.x*4 + w;
  {
    float4 hv = *(const float4*)&h2[(size_t)node*F1 + lane*4];
    *(float4*)&sh2[w][lane*4] = hv;
  }
  __syncthreads();
  float acc = 0.f;
  if(lane < NC){
    #pragma unroll 8
    for(int k=0; k<F1; k++) acc += sh2[w][k] * w2s[k*NC + lane];
  }
  float av = (lane < NC) ? as2[lane] : 0.f;
  float dv = (lane < NC) ? ad2[lane] : 0.f;
  float ps = acc*av, pd = acc*dv;
  #pragma unroll
  for(int off=1; off<64; off<<=1){ ps += __shfl_xor(ps,off,64); pd += __shfl_xor(pd,off,64); }
  if(lane < NC) h2p[(size_t)node*NC + lane] = acc;
  if(lane == 0){ aS2[node] = ps; aD2[node] = pd; }
}

// ---- layer-2 aggregation -> output (f32)
__global__ __launch_bounds__(256) void k_agg2(const float* __restrict__ h2p,
  const float* __restrict__ aS2, const float* __restrict__ aD2,
  const int* __restrict__ rowptr, const int* __restrict__ adj,
  const float* __restrict__ b2, float* __restrict__ out){
  int lane = threadIdx.x & 63;
  int node = blockIdx.x*4 + (threadIdx.x >> 6);
  int beg = rowptr[node], end = rowptr[node+1];
  float adv = aD2[node];
  float m = -1e30f, sden = 0.f;
  for(int e=beg+lane; e<end; e+=64){
    int src = adj[e];
    float ev = aS2[src] + adv; ev = ev > 0.f ? ev : SLOPE*ev;
    if(ev > m){ sden = sden*__expf(m-ev) + 1.f; m = ev; }
    else sden += __expf(ev - m);
  }
  if(lane == 0){
    float ev = aS2[node] + adv; ev = ev > 0.f ? ev : SLOPE*ev;
    if(ev > m){ sden = sden*__expf(m-ev) + 1.f; m = ev; }
    else sden += __expf(ev - m);
  }
  #pragma unroll
  for(int off=1; off<64; off<<=1){
    float m2 = __shfl_xor(m,off,64), s2 = __shfl_xor(sden,off,64);
    float M = fmaxf(m, m2);
    sden = sden*__expf(m-M) + s2*__expf(m2-M);
    m = M;
  }
  float inv = 1.f/(sden + 1e-16f);
  float acc = 0.f;
  for(int e=beg; e<end; e++){
    int src = adj[e];
    float ev = aS2[src] + adv; ev = ev > 0.f ? ev : SLOPE*ev;
    float al = __expf(ev - m) * inv;
    if(lane < NC) acc += al * h2p[(size_t)src*NC + lane];
  }
  {
    float ev = aS2[node] + adv; ev = ev > 0.f ? ev : SLOPE*ev;
    float al = __expf(ev - m) * inv;
    if(lane < NC) acc += al * h2p[(size_t)node*NC + lane];
  }
  if(lane < NC) out[(size_t)node*NC + lane] = acc + b2[lane];
}

extern "C" void kernel_launch(void* const* d_in, const int* in_sizes, int n_in,
                              void* d_out, int out_size, void* d_ws, size_t ws_size,
                              hipStream_t stream){
  (void)in_sizes; (void)n_in; (void)out_size; (void)ws_size;
  const float* x   = (const float*)d_in[0];
  const int*   ei  = (const int*)d_in[1];
  const float* W1  = (const float*)d_in[2];
  const float* as1 = (const float*)d_in[3];
  const float* ad1 = (const float*)d_in[4];
  const float* b1  = (const float*)d_in[5];
  const float* g1  = (const float*)d_in[6];
  const float* be1 = (const float*)d_in[7];
  const float* mn1 = (const float*)d_in[8];
  const float* vr1 = (const float*)d_in[9];
  const float* W2  = (const float*)d_in[10];
  const float* as2 = (const float*)d_in[11];
  const float* ad2 = (const float*)d_in[12];
  const float* b2  = (const float*)d_in[13];

  char* ws = (char*)d_ws;
  float* h1    = (float*)(ws + 0);            // 51,200,000
  // xh/xl live in h2's space (dead once k_gemm1 completes; h2 written later by k_agg1)
  u16*  xh     = (u16*) (ws + 51200000);      // 25,600,000
  u16*  xl     = (u16*) (ws + 76800000);      // 25,600,000
  float* h2    = (float*)(ws + 51200000);     // 51,200,000 (aliases xh/xl)
  // W1t hi/lo live in h2p's space (dead once k_gemm1 completes; h2p written by k_gemm2)
  u16*  w1h    = (u16*) (ws + 102400000);     //    131,072
  u16*  w1l    = (u16*) (ws + 102531072);     //    131,072
  float* h2p   = (float*)(ws + 102400000);    //  8,000,000 (aliases w1h/w1l)
  float* aS1   = (float*)(ws + 110400000);    //    800,000
  float* aD1   = (float*)(ws + 111200000);    //    800,000
  float* aS2   = (float*)(ws + 112000000);    //    200,000
  float* aD2   = (float*)(ws + 112200000);    //    200,000
  int*  rowptr = (int*)  (ws + 112400000);    //    200,016
  int*  rowfill= (int*)  (ws + 112600016);    //    200,000
  int*  adj    = (int*)  (ws + 112800016);    //  6,400,000
  int*  flags  = (int*)  (ws + 119200016);    //         16

  hipMemsetAsync(rowfill, 0, NN*sizeof(int), stream);
  k_detect<<<1, 256, 0, stream>>>(ei, flags);
  k_count <<<(NE+255)/256, 256, 0, stream>>>(ei, flags, rowfill);
  k_scan  <<<1, 1024, 0, stream>>>(rowfill, rowptr);
  k_fill  <<<(NE+255)/256, 256, 0, stream>>>(ei, flags, rowfill, adj);
  k_splitx<<<NN*FIN/8/256, 256, 0, stream>>>(x, xh, xl);
  k_tw1   <<<256, 256, 0, stream>>>(W1, w1h, w1l);
  k_gemm1 <<<(NN+63)/64, 256, 0, stream>>>((const short*)xh, (const short*)xl,
                                           (const short*)w1h, (const short*)w1l, h1);
  k_att1  <<<NN/4, 256, 0, stream>>>(h1, as1, ad1, aS1, aD1);
  k_agg1  <<<NN/4, 256, 0, stream>>>(h1, aS1, aD1, rowptr, adj, b1, g1, be1, mn1, vr1, h2);
  k_gemm2 <<<NN/4, 256, 0, stream>>>(h2, W2, as2, ad2, h2p, aS2, aD2);
  k_agg2  <<<NN/4, 256, 0, stream>>>(h2p, aS2, aD2, rowptr, adj, b2, (float*)d_out);
}

// Round 4
// 945.248 us; speedup vs baseline: 9.6107x; 1.0620x over previous
//
#include <hip/hip_runtime.h>
#include <hip/hip_bf16.h>

#define NN 50000
#define FIN 256
#define F1 256      // HEADS*HID
#define HEADS 4
#define HID 64
#define NC 40
#define NE 1600000
#define SLOPE 0.2f
#define LOG2E 1.44269504f

typedef unsigned int u32;
typedef unsigned short u16;
typedef __attribute__((ext_vector_type(8))) short bf16x8;
typedef __attribute__((ext_vector_type(4))) float f32x4;

__device__ __forceinline__ float us2f(u32 u){ u32 b = u << 16; return __uint_as_float(b); }
__device__ __forceinline__ u16 f2bf(float f){
  u32 b = __float_as_uint(f);
  u32 r = (b + 0x7fffu + ((b >> 16) & 1u)) >> 16;
  return (u16)r;
}
__device__ __forceinline__ int ld_src(const int* ei, int i, int i64){ return i64 ? ei[2*i] : ei[i]; }
__device__ __forceinline__ int ld_dst(const int* ei, int i, int i64){ return i64 ? ei[2*(NE+i)] : ei[NE+i]; }

// ---- int-width detection: flags[1]=1 if edge_index is int64 on device
__global__ void k_detect(const int* ei, int* flags){
  __shared__ int ci;
  if(threadIdx.x==0) ci=0;
  __syncthreads();
  if(ei[2*threadIdx.x+1] != 0) atomicAdd(&ci, 1);
  __syncthreads();
  if(threadIdx.x==0){ flags[0] = 0; flags[1] = (ci == 0) ? 1 : 0; }
}

// ---- CSR build
__global__ void k_count(const int* __restrict__ ei, const int* __restrict__ flags, int* __restrict__ deg){
  int i64 = flags[1];
  int i = blockIdx.x*256 + threadIdx.x;
  if(i < NE) atomicAdd(&deg[ld_dst(ei,i,i64)], 1);
}

__global__ __launch_bounds__(1024) void k_scan(int* __restrict__ degfill, int* __restrict__ rowptr){
  __shared__ int sums[1024];
  int t = threadIdx.x;
  const int C = (NN + 1023) / 1024;
  int base = t * C, s = 0;
  for(int j=0;j<C;j++){ int idx=base+j; if(idx<NN) s += degfill[idx]; }
  sums[t] = s; __syncthreads();
  for(int off=1; off<1024; off<<=1){
    int v = (t >= off) ? sums[t-off] : 0;
    __syncthreads();
    sums[t] += v;
    __syncthreads();
  }
  int run = (t==0) ? 0 : sums[t-1];
  for(int j=0;j<C;j++){
    int idx = base + j;
    if(idx < NN){ int d = degfill[idx]; rowptr[idx] = run; degfill[idx] = run; run += d; }
  }
  if(t==1023) rowptr[NN] = run;
}

__global__ void k_fill(const int* __restrict__ ei, const int* __restrict__ flags,
                       int* __restrict__ fill, int* __restrict__ adj){
  int i64 = flags[1];
  int i = blockIdx.x*256 + threadIdx.x;
  if(i < NE){
    int d = ld_dst(ei,i,i64);
    int p = atomicAdd(&fill[d], 1);
    adj[p] = ld_src(ei,i,i64);
  }
}

// ---- split x (f32) -> xh + xl (bf16 each)
__global__ void k_splitx(const float* __restrict__ x, u16* __restrict__ xh, u16* __restrict__ xl){
  int i = (blockIdx.x*256 + threadIdx.x) * 8;
  float4 a = *(const float4*)(x+i);
  float4 b = *(const float4*)(x+i+4);
  float v[8] = {a.x,a.y,a.z,a.w,b.x,b.y,b.z,b.w};
  u16 hi[8], lo[8];
  #pragma unroll
  for(int j=0;j<8;j++){
    u16 h = f2bf(v[j]);
    hi[j] = h;
    lo[j] = f2bf(v[j] - us2f(h));
  }
  *(ushort4*)&xh[i]   = make_ushort4(hi[0],hi[1],hi[2],hi[3]);
  *(ushort4*)&xh[i+4] = make_ushort4(hi[4],hi[5],hi[6],hi[7]);
  *(ushort4*)&xl[i]   = make_ushort4(lo[0],lo[1],lo[2],lo[3]);
  *(ushort4*)&xl[i+4] = make_ushort4(lo[4],lo[5],lo[6],lo[7]);
}

// ---- transpose + split W1 (f32 [k][n]) -> W1t hi/lo (bf16 [n][k])
__global__ void k_tw1(const float* __restrict__ W1, u16* __restrict__ wh, u16* __restrict__ wl){
  int id = blockIdx.x*256 + threadIdx.x;    // 65536 total
  int n = id & 255, k = id >> 8;
  float v = W1[k*F1 + n];
  u16 h = f2bf(v);
  wh[n*FIN + k] = h;
  wl[n*FIN + k] = f2bf(v - us2f(h));
}

// ---- GEMM1 (MFMA bf16x3) + fused attention dots.
// h1 stored bf16; aS/aD computed from f32 acc, pre-scaled by log2(e).
__global__ __launch_bounds__(256) void k_gemm1(const short* __restrict__ xh, const short* __restrict__ xl,
                                               const short* __restrict__ wh, const short* __restrict__ wl,
                                               const float* __restrict__ as1, const float* __restrict__ ad1,
                                               u16* __restrict__ h1b,
                                               float* __restrict__ aS, float* __restrict__ aD){
  int w = threadIdx.x >> 6, lane = threadIdx.x & 63;
  int lo = lane & 15, hi = lane >> 4;
  int rowbase = blockIdx.x*64 + w*16;
  int arow = rowbase + lo; if(arow >= NN) arow = NN-1;
  f32x4 acc[16];
  #pragma unroll
  for(int t=0;t<16;t++) acc[t] = (f32x4){0.f,0.f,0.f,0.f};
  const short* xph = xh + (size_t)arow*FIN + 8*hi;
  const short* xpl = xl + (size_t)arow*FIN + 8*hi;
  const short* wph = wh + (size_t)lo*FIN + 8*hi;
  const short* wpl = wl + (size_t)lo*FIN + 8*hi;
  for(int k0=0; k0<FIN; k0+=32){
    bf16x8 ah = *(const bf16x8*)(xph + k0);
    bf16x8 al = *(const bf16x8*)(xpl + k0);
    #pragma unroll
    for(int t=0;t<16;t++){
      bf16x8 bh = *(const bf16x8*)(wph + (size_t)t*16*FIN + k0);
      bf16x8 bl = *(const bf16x8*)(wpl + (size_t)t*16*FIN + k0);
      acc[t] = __builtin_amdgcn_mfma_f32_16x16x32_bf16(ah, bh, acc[t], 0, 0, 0);
      acc[t] = __builtin_amdgcn_mfma_f32_16x16x32_bf16(al, bh, acc[t], 0, 0, 0);
      acc[t] = __builtin_amdgcn_mfma_f32_16x16x32_bf16(ah, bl, acc[t], 0, 0, 0);
    }
  }
  // h1 store (bf16)
  #pragma unroll
  for(int t=0;t<16;t++){
    #pragma unroll
    for(int r=0;r<4;r++){
      int row = rowbase + hi*4 + r;
      if(row < NN) h1b[(size_t)row*F1 + t*16 + lo] = f2bf(acc[t][r]);
    }
  }
  // fused attention dots: head of col c=t*16+lo is t>>2; flat att index == c
  float ps[4][4], pd[4][4];
  #pragma unroll
  for(int q=0;q<4;q++){
    #pragma unroll
    for(int r=0;r<4;r++){ ps[q][r]=0.f; pd[q][r]=0.f; }
  }
  #pragma unroll
  for(int t=0;t<16;t++){
    float sv = as1[t*16+lo]*LOG2E, dv = ad1[t*16+lo]*LOG2E;
    #pragma unroll
    for(int r=0;r<4;r++){ ps[t>>2][r] += acc[t][r]*sv; pd[t>>2][r] += acc[t][r]*dv; }
  }
  #pragma unroll
  for(int off=1; off<16; off<<=1){
    #pragma unroll
    for(int q=0;q<4;q++){
      #pragma unroll
      for(int r=0;r<4;r++){
        ps[q][r] += __shfl_xor(ps[q][r], off, 64);
        pd[q][r] += __shfl_xor(pd[q][r], off, 64);
      }
    }
  }
  if(lo == 0){
    #pragma unroll
    for(int q=0;q<4;q++){
      #pragma unroll
      for(int r=0;r<4;r++){
        int row = rowbase + hi*4 + r;
        if(row < NN){ aS[row*HEADS+q] = ps[q][r]; aD[row*HEADS+q] = pd[q][r]; }
      }
    }
  }
}

// ---- layer-1 aggregation + bias + BN + ELU -> h2 (f32), one wave per node.
// Phase 1: pure max of prescaled aS (lrelu/exp deferred by monotonicity).
// Phase 2: unnormalized accumulate + denominator, single exp per edge.
__global__ __launch_bounds__(256) void k_agg1(const u16* __restrict__ h1b,
  const float* __restrict__ aS, const float* __restrict__ aD,
  const int* __restrict__ rowptr, const int* __restrict__ adj,
  const float* __restrict__ b1, const float* __restrict__ g1, const float* __restrict__ be1,
  const float* __restrict__ mn1, const float* __restrict__ vr1,
  float* __restrict__ h2){
  int lane = threadIdx.x & 63;
  int node = blockIdx.x*4 + (threadIdx.x >> 6);
  int h = lane >> 4;
  int beg = rowptr[node], end = rowptr[node+1];
  float4 ad4 = *(const float4*)&aD[node*HEADS];
  float adh[4] = {ad4.x, ad4.y, ad4.z, ad4.w};
  // phase 1: max over {in-edges, self} of aS'
  float4 s4 = *(const float4*)&aS[node*HEADS];
  float M[4] = {s4.x, s4.y, s4.z, s4.w};
  for(int e=beg+lane; e<end; e+=64){
    int src = adj[e];
    float4 v = *(const float4*)&aS[src*HEADS];
    M[0]=fmaxf(M[0],v.x); M[1]=fmaxf(M[1],v.y); M[2]=fmaxf(M[2],v.z); M[3]=fmaxf(M[3],v.w);
  }
  #pragma unroll
  for(int off=1; off<64; off<<=1){
    #pragma unroll
    for(int q=0;q<4;q++) M[q] = fmaxf(M[q], __shfl_xor(M[q], off, 64));
  }
  float adhh = adh[h];
  float mh; { float t = M[h] + adhh; mh = t > 0.f ? t : SLOPE*t; }
  // phase 2: serial over edges, unnormalized
  float den = 0.f, a0=0.f, a1=0.f, a2=0.f, a3=0.f;
  for(int e=beg; e<end; e++){
    int src = adj[e];
    float ev = aS[src*HEADS + h] + adhh;
    ev = ev > 0.f ? ev : SLOPE*ev;
    float wgt = exp2f(ev - mh);
    den += wgt;
    ushort4 hv = *(const ushort4*)&h1b[(size_t)src*F1 + lane*4];
    a0 += wgt*us2f(hv.x); a1 += wgt*us2f(hv.y); a2 += wgt*us2f(hv.z); a3 += wgt*us2f(hv.w);
  }
  { // self loop
    float ev = aS[node*HEADS + h] + adhh;
    ev = ev > 0.f ? ev : SLOPE*ev;
    float wgt = exp2f(ev - mh);
    den += wgt;
    ushort4 hv = *(const ushort4*)&h1b[(size_t)node*F1 + lane*4];
    a0 += wgt*us2f(hv.x); a1 += wgt*us2f(hv.y); a2 += wgt*us2f(hv.z); a3 += wgt*us2f(hv.w);
  }
  float inv = 1.f/den;
  int c = lane*4;
  float o[4] = {a0*inv, a1*inv, a2*inv, a3*inv};
  #pragma unroll
  for(int j=0;j<4;j++){
    float v = o[j] + b1[c+j];
    v = (v - mn1[c+j]) * rsqrtf(vr1[c+j] + 1e-5f) * g1[c+j] + be1[c+j];
    v = v > 0.f ? v : (__expf(v) - 1.f);            // ELU
    o[j] = v;
  }
  *(float4*)&h2[(size_t)node*F1 + c] = make_float4(o[0],o[1],o[2],o[3]);
}

// ---- GEMM2 (8 waves/block, 8 nodes) + attention dots layer 2 (prescaled)
__global__ __launch_bounds__(512) void k_gemm2(const float* __restrict__ h2, const float* __restrict__ W2,
    const float* __restrict__ as2, const float* __restrict__ ad2,
    float* __restrict__ h2p, float* __restrict__ aS2, float* __restrict__ aD2){
  __shared__ float w2s[F1*NC];          // 40 KB
  __shared__ float sh2[8][F1];          // 8 KB
  for(int i=threadIdx.x; i<F1*NC; i+=512) w2s[i] = W2[i];
  int w = threadIdx.x >> 6, lane = threadIdx.x & 63;
  int node = blockIdx.x*8 + w;
  {
    float4 hv = *(const float4*)&h2[(size_t)node*F1 + lane*4];
    *(float4*)&sh2[w][lane*4] = hv;
  }
  __syncthreads();
  float acc = 0.f;
  if(lane < NC){
    #pragma unroll 8
    for(int k=0; k<F1; k++) acc += sh2[w][k] * w2s[k*NC + lane];
  }
  float av = (lane < NC) ? as2[lane] : 0.f;
  float dv = (lane < NC) ? ad2[lane] : 0.f;
  float ps = acc*av, pd = acc*dv;
  #pragma unroll
  for(int off=1; off<64; off<<=1){ ps += __shfl_xor(ps,off,64); pd += __shfl_xor(pd,off,64); }
  if(lane < NC) h2p[(size_t)node*NC + lane] = acc;
  if(lane == 0){ aS2[node] = ps*LOG2E; aD2[node] = pd*LOG2E; }
}

// ---- layer-2 aggregation -> output (f32), max-trick + unnormalized
__global__ __launch_bounds__(256) void k_agg2(const float* __restrict__ h2p,
  const float* __restrict__ aS2, const float* __restrict__ aD2,
  const int* __restrict__ rowptr, const int* __restrict__ adj,
  const float* __restrict__ b2, float* __restrict__ out){
  int lane = threadIdx.x & 63;
  int node = blockIdx.x*4 + (threadIdx.x >> 6);
  int beg = rowptr[node], end = rowptr[node+1];
  float adv = aD2[node];
  float M = aS2[node];
  for(int e=beg+lane; e<end; e+=64){
    int src = adj[e];
    M = fmaxf(M, aS2[src]);
  }
  #pragma unroll
  for(int off=1; off<64; off<<=1) M = fmaxf(M, __shfl_xor(M, off, 64));
  float m; { float t = M + adv; m = t > 0.f ? t : SLOPE*t; }
  float den = 0.f, acc = 0.f;
  for(int e=beg; e<end; e++){
    int src = adj[e];
    float ev = aS2[src] + adv; ev = ev > 0.f ? ev : SLOPE*ev;
    float wgt = exp2f(ev - m);
    den += wgt;
    if(lane < NC) acc += wgt * h2p[(size_t)src*NC + lane];
  }
  {
    float ev = aS2[node] + adv; ev = ev > 0.f ? ev : SLOPE*ev;
    float wgt = exp2f(ev - m);
    den += wgt;
    if(lane < NC) acc += wgt * h2p[(size_t)node*NC + lane];
  }
  if(lane < NC) out[(size_t)node*NC + lane] = acc/den + b2[lane];
}

extern "C" void kernel_launch(void* const* d_in, const int* in_sizes, int n_in,
                              void* d_out, int out_size, void* d_ws, size_t ws_size,
                              hipStream_t stream){
  (void)in_sizes; (void)n_in; (void)out_size; (void)ws_size;
  const float* x   = (const float*)d_in[0];
  const int*   ei  = (const int*)d_in[1];
  const float* W1  = (const float*)d_in[2];
  const float* as1 = (const float*)d_in[3];
  const float* ad1 = (const float*)d_in[4];
  const float* b1  = (const float*)d_in[5];
  const float* g1  = (const float*)d_in[6];
  const float* be1 = (const float*)d_in[7];
  const float* mn1 = (const float*)d_in[8];
  const float* vr1 = (const float*)d_in[9];
  const float* W2  = (const float*)d_in[10];
  const float* as2 = (const float*)d_in[11];
  const float* ad2 = (const float*)d_in[12];
  const float* b2  = (const float*)d_in[13];

  char* ws = (char*)d_ws;
  u16*  h1b    = (u16*) (ws + 0);             // 25,600,000 (bf16 h1)
  float* h2    = (float*)(ws + 25600000);     // 51,200,000
  // xh/xl alias h2 (dead once k_gemm1 completes; h2 written later by k_agg1)
  u16*  xh     = (u16*) (ws + 25600000);      // 25,600,000
  u16*  xl     = (u16*) (ws + 51200000);      // 25,600,000
  // w1h/w1l alias h2p (dead before k_gemm2 writes h2p)
  float* h2p   = (float*)(ws + 76800000);     //  8,000,000
  u16*  w1h    = (u16*) (ws + 76800000);      //    131,072
  u16*  w1l    = (u16*) (ws + 76931072);      //    131,072
  float* aS1   = (float*)(ws + 84800000);     //    800,000
  float* aD1   = (float*)(ws + 85600000);     //    800,000
  float* aS2   = (float*)(ws + 86400000);     //    200,000
  float* aD2   = (float*)(ws + 86600000);     //    200,000
  int*  rowptr = (int*)  (ws + 86800000);     //    200,016
  int*  rowfill= (int*)  (ws + 87000016);     //    200,000
  int*  adj    = (int*)  (ws + 87200016);     //  6,400,000
  int*  flags  = (int*)  (ws + 93600016);     //         16

  hipMemsetAsync(rowfill, 0, NN*sizeof(int), stream);
  k_detect<<<1, 256, 0, stream>>>(ei, flags);
  k_count <<<(NE+255)/256, 256, 0, stream>>>(ei, flags, rowfill);
  k_scan  <<<1, 1024, 0, stream>>>(rowfill, rowptr);
  k_fill  <<<(NE+255)/256, 256, 0, stream>>>(ei, flags, rowfill, adj);
  k_splitx<<<NN*FIN/8/256, 256, 0, stream>>>(x, xh, xl);
  k_tw1   <<<256, 256, 0, stream>>>(W1, w1h, w1l);
  k_gemm1 <<<(NN+63)/64, 256, 0, stream>>>((const short*)xh, (const short*)xl,
                                           (const short*)w1h, (const short*)w1l,
                                           as1, ad1, h1b, aS1, aD1);
  k_agg1  <<<NN/4, 256, 0, stream>>>(h1b, aS1, aD1, rowptr, adj, b1, g1, be1, mn1, vr1, h2);
  k_gemm2 <<<NN/8, 512, 0, stream>>>(h2, W2, as2, ad2, h2p, aS2, aD2);
  k_agg2  <<<NN/4, 256, 0, stream>>>(h2p, aS2, aD2, rowptr, adj, b2, (float*)d_out);
}

// Round 5
// 758.154 us; speedup vs baseline: 11.9824x; 1.2468x over previous
//
#include <hip/hip_runtime.h>
#include <hip/hip_bf16.h>

#define NN 50000
#define FIN 256
#define F1 256      // HEADS*HID
#define HEADS 4
#define HID 64
#define NC 40
#define NE 1600000
#define SLOPE 0.2f
#define LOG2E 1.44269504f
#define CHUNK 128

typedef unsigned int u32;
typedef unsigned short u16;
typedef __attribute__((ext_vector_type(8))) short bf16x8;
typedef __attribute__((ext_vector_type(4))) float f32x4;

__device__ __forceinline__ float us2f(u32 u){ u32 b = u << 16; return __uint_as_float(b); }
__device__ __forceinline__ u16 f2bf(float f){
  u32 b = __float_as_uint(f);
  u32 r = (b + 0x7fffu + ((b >> 16) & 1u)) >> 16;
  return (u16)r;
}
__device__ __forceinline__ int ld_src(const int* ei, int i, int i64){ return i64 ? ei[2*i] : ei[i]; }
__device__ __forceinline__ int ld_dst(const int* ei, int i, int i64){ return i64 ? ei[2*(NE+i)] : ei[NE+i]; }

// ---- int-width detection: flags[1]=1 if edge_index is int64 on device
__global__ void k_detect(const int* ei, int* flags){
  __shared__ int ci;
  if(threadIdx.x==0) ci=0;
  __syncthreads();
  if(ei[2*threadIdx.x+1] != 0) atomicAdd(&ci, 1);
  __syncthreads();
  if(threadIdx.x==0){ flags[0] = 0; flags[1] = (ci == 0) ? 1 : 0; }
}

// ---- CSR build
__global__ void k_count(const int* __restrict__ ei, const int* __restrict__ flags, int* __restrict__ deg){
  int i64 = flags[1];
  int i = blockIdx.x*256 + threadIdx.x;
  if(i < NE) atomicAdd(&deg[ld_dst(ei,i,i64)], 1);
}

__global__ __launch_bounds__(1024) void k_scan(int* __restrict__ degfill, int* __restrict__ rowptr){
  __shared__ int sums[1024];
  int t = threadIdx.x;
  const int C = (NN + 1023) / 1024;
  int base = t * C, s = 0;
  for(int j=0;j<C;j++){ int idx=base+j; if(idx<NN) s += degfill[idx]; }
  sums[t] = s; __syncthreads();
  for(int off=1; off<1024; off<<=1){
    int v = (t >= off) ? sums[t-off] : 0;
    __syncthreads();
    sums[t] += v;
    __syncthreads();
  }
  int run = (t==0) ? 0 : sums[t-1];
  for(int j=0;j<C;j++){
    int idx = base + j;
    if(idx < NN){ int d = degfill[idx]; rowptr[idx] = run; degfill[idx] = run; run += d; }
  }
  if(t==1023) rowptr[NN] = run;
}

__global__ void k_fill(const int* __restrict__ ei, const int* __restrict__ flags,
                       int* __restrict__ fill, int* __restrict__ adj){
  int i64 = flags[1];
  int i = blockIdx.x*256 + threadIdx.x;
  if(i < NE){
    int d = ld_dst(ei,i,i64);
    int p = atomicAdd(&fill[d], 1);
    adj[p] = ld_src(ei,i,i64);
  }
}

// ---- transpose + split W1 (f32 [k][n]) -> W1t hi/lo (bf16 [n][k])
__global__ void k_tw1(const float* __restrict__ W1, u16* __restrict__ wh, u16* __restrict__ wl){
  int id = blockIdx.x*256 + threadIdx.x;    // 65536 total
  int n = id & 255, k = id >> 8;
  float v = W1[k*F1 + n];
  u16 h = f2bf(v);
  wh[n*FIN + k] = h;
  wl[n*FIN + k] = f2bf(v - us2f(h));
}

// ---- GEMM1 (MFMA bf16x3, on-the-fly x split) + fused attention dots.
__global__ __launch_bounds__(256) void k_gemm1(const float* __restrict__ x,
                                               const short* __restrict__ wh, const short* __restrict__ wl,
                                               const float* __restrict__ as1, const float* __restrict__ ad1,
                                               u16* __restrict__ h1b,
                                               float* __restrict__ aS, float* __restrict__ aD){
  int w = threadIdx.x >> 6, lane = threadIdx.x & 63;
  int lo = lane & 15, hi = lane >> 4;
  int rowbase = blockIdx.x*64 + w*16;
  int arow = rowbase + lo; if(arow >= NN) arow = NN-1;
  f32x4 acc[16];
  #pragma unroll
  for(int t=0;t<16;t++) acc[t] = (f32x4){0.f,0.f,0.f,0.f};
  const float* xp = x + (size_t)arow*FIN + 8*hi;
  const short* wph = wh + (size_t)lo*FIN + 8*hi;
  const short* wpl = wl + (size_t)lo*FIN + 8*hi;
  for(int k0=0; k0<FIN; k0+=32){
    float4 va = *(const float4*)(xp + k0);
    float4 vb = *(const float4*)(xp + k0 + 4);
    float v[8] = {va.x,va.y,va.z,va.w,vb.x,vb.y,vb.z,vb.w};
    bf16x8 ah, al;
    #pragma unroll
    for(int j=0;j<8;j++){
      u32 u = __float_as_uint(v[j]);
      ah[j] = (short)(u >> 16);                       // truncate hi
      float hf = __uint_as_float(u & 0xffff0000u);
      al[j] = (short)(__float_as_uint(v[j] - hf) >> 16);  // truncate lo
    }
    #pragma unroll
    for(int t=0;t<16;t++){
      bf16x8 bh = *(const bf16x8*)(wph + (size_t)t*16*FIN + k0);
      bf16x8 bl = *(const bf16x8*)(wpl + (size_t)t*16*FIN + k0);
      acc[t] = __builtin_amdgcn_mfma_f32_16x16x32_bf16(ah, bh, acc[t], 0, 0, 0);
      acc[t] = __builtin_amdgcn_mfma_f32_16x16x32_bf16(al, bh, acc[t], 0, 0, 0);
      acc[t] = __builtin_amdgcn_mfma_f32_16x16x32_bf16(ah, bl, acc[t], 0, 0, 0);
    }
  }
  // h1 store (bf16)
  #pragma unroll
  for(int t=0;t<16;t++){
    #pragma unroll
    for(int r=0;r<4;r++){
      int row = rowbase + hi*4 + r;
      if(row < NN) h1b[(size_t)row*F1 + t*16 + lo] = f2bf(acc[t][r]);
    }
  }
  // fused attention dots (prescaled by log2 e)
  float ps[4][4], pd[4][4];
  #pragma unroll
  for(int q=0;q<4;q++){
    #pragma unroll
    for(int r=0;r<4;r++){ ps[q][r]=0.f; pd[q][r]=0.f; }
  }
  #pragma unroll
  for(int t=0;t<16;t++){
    float sv = as1[t*16+lo]*LOG2E, dv = ad1[t*16+lo]*LOG2E;
    #pragma unroll
    for(int r=0;r<4;r++){ ps[t>>2][r] += acc[t][r]*sv; pd[t>>2][r] += acc[t][r]*dv; }
  }
  #pragma unroll
  for(int off=1; off<16; off<<=1){
    #pragma unroll
    for(int q=0;q<4;q++){
      #pragma unroll
      for(int r=0;r<4;r++){
        ps[q][r] += __shfl_xor(ps[q][r], off, 64);
        pd[q][r] += __shfl_xor(pd[q][r], off, 64);
      }
    }
  }
  if(lo == 0){
    #pragma unroll
    for(int q=0;q<4;q++){
      #pragma unroll
      for(int r=0;r<4;r++){
        int row = rowbase + hi*4 + r;
        if(row < NN){ aS[row*HEADS+q] = ps[q][r]; aD[row*HEADS+q] = pd[q][r]; }
      }
    }
  }
}

// ---- layer-1 aggregation + bias + BN + ELU -> h2 (f32), one wave per node.
// No max pass (softmax shift-invariant; args bounded, clamp for inf-safety).
// Phase A (parallel): per-edge weights+den -> LDS. Phase B (serial): gather+fma.
__global__ __launch_bounds__(256) void k_agg1(const u16* __restrict__ h1b,
  const float* __restrict__ aS, const float* __restrict__ aD,
  const int* __restrict__ rowptr, const int* __restrict__ adj,
  const float* __restrict__ b1, const float* __restrict__ g1, const float* __restrict__ be1,
  const float* __restrict__ mn1, const float* __restrict__ vr1,
  float* __restrict__ h2){
  __shared__ float lw[4][CHUNK*4];   // [wave][i*4+head]
  __shared__ int   lsrc[4][CHUNK];
  int w = threadIdx.x >> 6, lane = threadIdx.x & 63;
  int node = blockIdx.x*4 + w;
  int h = lane >> 4;
  int beg = rowptr[node], end = rowptr[node+1];
  float4 ad4 = *(const float4*)&aD[node*HEADS];
  float den[4] = {0.f,0.f,0.f,0.f};
  float a0=0.f, a1=0.f, a2=0.f, a3=0.f;
  int total = end - beg + 1;                  // + self loop
  for(int c0=0; c0<total; c0+=CHUNK){
    int n = min(CHUNK, total - c0);
    for(int i=lane; i<n; i+=64){
      int e = beg + c0 + i;
      int src = (e < end) ? adj[e] : node;
      float4 s4 = *(const float4*)&aS[src*HEADS];
      float w0 = s4.x + ad4.x; w0 = w0>0.f?w0:SLOPE*w0; w0 = exp2f(fminf(w0,110.f));
      float w1 = s4.y + ad4.y; w1 = w1>0.f?w1:SLOPE*w1; w1 = exp2f(fminf(w1,110.f));
      float w2 = s4.z + ad4.z; w2 = w2>0.f?w2:SLOPE*w2; w2 = exp2f(fminf(w2,110.f));
      float w3 = s4.w + ad4.w; w3 = w3>0.f?w3:SLOPE*w3; w3 = exp2f(fminf(w3,110.f));
      lsrc[w][i] = src;
      *(float4*)&lw[w][i*4] = make_float4(w0,w1,w2,w3);
      den[0]+=w0; den[1]+=w1; den[2]+=w2; den[3]+=w3;
    }
    asm volatile("s_waitcnt lgkmcnt(0)" ::: "memory");
    #pragma unroll 2
    for(int i=0;i<n;i++){
      int s = lsrc[w][i];
      float wg = lw[w][i*4+h];
      ushort4 hv = *(const ushort4*)&h1b[(size_t)s*F1 + lane*4];
      a0 += wg*us2f(hv.x); a1 += wg*us2f(hv.y); a2 += wg*us2f(hv.z); a3 += wg*us2f(hv.w);
    }
  }
  #pragma unroll
  for(int off=1; off<64; off<<=1){
    #pragma unroll
    for(int q=0;q<4;q++) den[q] += __shfl_xor(den[q], off, 64);
  }
  float inv = 1.f/(den[h] + 1e-16f);
  int c = lane*4;
  float o[4] = {a0*inv, a1*inv, a2*inv, a3*inv};
  #pragma unroll
  for(int j=0;j<4;j++){
    float v = o[j] + b1[c+j];
    v = (v - mn1[c+j]) * rsqrtf(vr1[c+j] + 1e-5f) * g1[c+j] + be1[c+j];
    v = v > 0.f ? v : (__expf(v) - 1.f);            // ELU
    o[j] = v;
  }
  *(float4*)&h2[(size_t)node*F1 + c] = make_float4(o[0],o[1],o[2],o[3]);
}

// ---- GEMM2 (8 waves/block) + attention dots layer 2 (prescaled)
__global__ __launch_bounds__(512) void k_gemm2(const float* __restrict__ h2, const float* __restrict__ W2,
    const float* __restrict__ as2, const float* __restrict__ ad2,
    float* __restrict__ h2p, float* __restrict__ aS2, float* __restrict__ aD2){
  __shared__ float w2s[F1*NC];          // 40 KB
  __shared__ float sh2[8][F1];          // 8 KB
  for(int i=threadIdx.x; i<F1*NC; i+=512) w2s[i] = W2[i];
  int w = threadIdx.x >> 6, lane = threadIdx.x & 63;
  int node = blockIdx.x*8 + w;
  {
    float4 hv = *(const float4*)&h2[(size_t)node*F1 + lane*4];
    *(float4*)&sh2[w][lane*4] = hv;
  }
  __syncthreads();
  float acc = 0.f;
  if(lane < NC){
    #pragma unroll 8
    for(int k=0; k<F1; k++) acc += sh2[w][k] * w2s[k*NC + lane];
  }
  float av = (lane < NC) ? as2[lane] : 0.f;
  float dv = (lane < NC) ? ad2[lane] : 0.f;
  float ps = acc*av, pd = acc*dv;
  #pragma unroll
  for(int off=1; off<64; off<<=1){ ps += __shfl_xor(ps,off,64); pd += __shfl_xor(pd,off,64); }
  if(lane < NC) h2p[(size_t)node*NC + lane] = acc;
  if(lane == 0){ aS2[node] = ps*LOG2E; aD2[node] = pd*LOG2E; }
}

// ---- layer-2 aggregation -> output (f32), no max pass, LDS weights
__global__ __launch_bounds__(256) void k_agg2(const float* __restrict__ h2p,
  const float* __restrict__ aS2, const float* __restrict__ aD2,
  const int* __restrict__ rowptr, const int* __restrict__ adj,
  const float* __restrict__ b2, float* __restrict__ out){
  __shared__ float lw[4][CHUNK];
  __shared__ int   lsrc[4][CHUNK];
  int w = threadIdx.x >> 6, lane = threadIdx.x & 63;
  int node = blockIdx.x*4 + w;
  int beg = rowptr[node], end = rowptr[node+1];
  float adv = aD2[node];
  float den = 0.f, acc = 0.f;
  int total = end - beg + 1;
  for(int c0=0; c0<total; c0+=CHUNK){
    int n = min(CHUNK, total - c0);
    for(int i=lane; i<n; i+=64){
      int e = beg + c0 + i;
      int src = (e < end) ? adj[e] : node;
      float ev = aS2[src] + adv; ev = ev>0.f?ev:SLOPE*ev;
      float wg = exp2f(fminf(ev,110.f));
      lsrc[w][i] = src;
      lw[w][i] = wg;
      den += wg;
    }
    asm volatile("s_waitcnt lgkmcnt(0)" ::: "memory");
    #pragma unroll 2
    for(int i=0;i<n;i++){
      int s = lsrc[w][i];
      float wg = lw[w][i];
      if(lane < NC) acc += wg * h2p[(size_t)s*NC + lane];
    }
  }
  #pragma unroll
  for(int off=1; off<64; off<<=1) den += __shfl_xor(den, off, 64);
  if(lane < NC) out[(size_t)node*NC + lane] = acc/(den + 1e-16f) + b2[lane];
}

extern "C" void kernel_launch(void* const* d_in, const int* in_sizes, int n_in,
                              void* d_out, int out_size, void* d_ws, size_t ws_size,
                              hipStream_t stream){
  (void)in_sizes; (void)n_in; (void)out_size; (void)ws_size;
  const float* x   = (const float*)d_in[0];
  const int*   ei  = (const int*)d_in[1];
  const float* W1  = (const float*)d_in[2];
  const float* as1 = (const float*)d_in[3];
  const float* ad1 = (const float*)d_in[4];
  const float* b1  = (const float*)d_in[5];
  const float* g1  = (const float*)d_in[6];
  const float* be1 = (const float*)d_in[7];
  const float* mn1 = (const float*)d_in[8];
  const float* vr1 = (const float*)d_in[9];
  const float* W2  = (const float*)d_in[10];
  const float* as2 = (const float*)d_in[11];
  const float* ad2 = (const float*)d_in[12];
  const float* b2  = (const float*)d_in[13];

  char* ws = (char*)d_ws;
  u16*  h1b    = (u16*) (ws + 0);             // 25,600,000 (bf16 h1)
  float* h2    = (float*)(ws + 25600000);     // 51,200,000
  // w1h/w1l alias h2p (dead before k_gemm2 writes h2p)
  float* h2p   = (float*)(ws + 76800000);     //  8,000,000
  u16*  w1h    = (u16*) (ws + 76800000);      //    131,072
  u16*  w1l    = (u16*) (ws + 76931072);      //    131,072
  float* aS1   = (float*)(ws + 84800000);     //    800,000
  float* aD1   = (float*)(ws + 85600000);     //    800,000
  float* aS2   = (float*)(ws + 86400000);     //    200,000
  float* aD2   = (float*)(ws + 86600000);     //    200,000
  int*  rowptr = (int*)  (ws + 86800000);     //    200,016
  int*  rowfill= (int*)  (ws + 87000016);     //    200,000
  int*  adj    = (int*)  (ws + 87200016);     //  6,400,000
  int*  flags  = (int*)  (ws + 93600016);     //         16

  hipMemsetAsync(rowfill, 0, NN*sizeof(int), stream);
  k_detect<<<1, 256, 0, stream>>>(ei, flags);
  k_count <<<(NE+255)/256, 256, 0, stream>>>(ei, flags, rowfill);
  k_scan  <<<1, 1024, 0, stream>>>(rowfill, rowptr);
  k_fill  <<<(NE+255)/256, 256, 0, stream>>>(ei, flags, rowfill, adj);
  k_tw1   <<<256, 256, 0, stream>>>(W1, w1h, w1l);
  k_gemm1 <<<(NN+63)/64, 256, 0, stream>>>(x, (const short*)w1h, (const short*)w1l,
                                           as1, ad1, h1b, aS1, aD1);
  k_agg1  <<<NN/4, 256, 0, stream>>>(h1b, aS1, aD1, rowptr, adj, b1, g1, be1, mn1, vr1, h2);
  k_gemm2 <<<NN/8, 512, 0, stream>>>(h2, W2, as2, ad2, h2p, aS2, aD2);
  k_agg2  <<<NN/4, 256, 0, stream>>>(h2p, aS2, aD2, rowptr, adj, b2, (float*)d_out);
}

// Round 6
// 713.335 us; speedup vs baseline: 12.7353x; 1.0628x over previous
//
#include <hip/hip_runtime.h>
#include <hip/hip_bf16.h>

#define NN 50000
#define FIN 256
#define F1 256      // HEADS*HID
#define HEADS 4
#define HID 64
#define NC 40
#define NE 1600000
#define SLOPE 0.2f
#define LOG2E 1.44269504f
#define CHUNK 128

typedef unsigned int u32;
typedef unsigned short u16;
typedef __attribute__((ext_vector_type(8))) short bf16x8;
typedef __attribute__((ext_vector_type(4))) float f32x4;

__device__ __forceinline__ float us2f(u32 u){ u32 b = u << 16; return __uint_as_float(b); }
__device__ __forceinline__ u16 f2bf(float f){
  u32 b = __float_as_uint(f);
  u32 r = (b + 0x7fffu + ((b >> 16) & 1u)) >> 16;
  return (u16)r;
}
__device__ __forceinline__ int ld_src(const int* ei, int i, int i64){ return i64 ? ei[2*i] : ei[i]; }
__device__ __forceinline__ int ld_dst(const int* ei, int i, int i64){ return i64 ? ei[2*(NE+i)] : ei[NE+i]; }

// ---- int-width detection: flags[1]=1 if edge_index is int64 on device
__global__ void k_detect(const int* ei, int* flags){
  __shared__ int ci;
  if(threadIdx.x==0) ci=0;
  __syncthreads();
  if(ei[2*threadIdx.x+1] != 0) atomicAdd(&ci, 1);
  __syncthreads();
  if(threadIdx.x==0){ flags[0] = 0; flags[1] = (ci == 0) ? 1 : 0; }
}

// ---- CSR build
__global__ void k_count(const int* __restrict__ ei, const int* __restrict__ flags, int* __restrict__ deg){
  int i64 = flags[1];
  int i = blockIdx.x*256 + threadIdx.x;
  if(i < NE) atomicAdd(&deg[ld_dst(ei,i,i64)], 1);
}

__global__ __launch_bounds__(1024) void k_scan(int* __restrict__ degfill, int* __restrict__ rowptr){
  __shared__ int sums[1024];
  int t = threadIdx.x;
  const int C = (NN + 1023) / 1024;
  int base = t * C, s = 0;
  for(int j=0;j<C;j++){ int idx=base+j; if(idx<NN) s += degfill[idx]; }
  sums[t] = s; __syncthreads();
  for(int off=1; off<1024; off<<=1){
    int v = (t >= off) ? sums[t-off] : 0;
    __syncthreads();
    sums[t] += v;
    __syncthreads();
  }
  int run = (t==0) ? 0 : sums[t-1];
  for(int j=0;j<C;j++){
    int idx = base + j;
    if(idx < NN){ int d = degfill[idx]; rowptr[idx] = run; degfill[idx] = run; run += d; }
  }
  if(t==1023) rowptr[NN] = run;
}

__global__ void k_fill(const int* __restrict__ ei, const int* __restrict__ flags,
                       int* __restrict__ fill, int* __restrict__ adj){
  int i64 = flags[1];
  int i = blockIdx.x*256 + threadIdx.x;
  if(i < NE){
    int d = ld_dst(ei,i,i64);
    int p = atomicAdd(&fill[d], 1);
    adj[p] = ld_src(ei,i,i64);
  }
}

// ---- split x (f32) -> xh + xl (bf16 each)
__global__ void k_splitx(const float* __restrict__ x, u16* __restrict__ xh, u16* __restrict__ xl){
  int i = (blockIdx.x*256 + threadIdx.x) * 8;
  float4 a = *(const float4*)(x+i);
  float4 b = *(const float4*)(x+i+4);
  float v[8] = {a.x,a.y,a.z,a.w,b.x,b.y,b.z,b.w};
  u16 hi[8], lo[8];
  #pragma unroll
  for(int j=0;j<8;j++){
    u32 u = __float_as_uint(v[j]);
    hi[j] = (u16)(u >> 16);                      // truncate hi
    float hf = __uint_as_float(u & 0xffff0000u);
    lo[j] = (u16)(__float_as_uint(v[j] - hf) >> 16);
  }
  *(ushort4*)&xh[i]   = make_ushort4(hi[0],hi[1],hi[2],hi[3]);
  *(ushort4*)&xh[i+4] = make_ushort4(hi[4],hi[5],hi[6],hi[7]);
  *(ushort4*)&xl[i]   = make_ushort4(lo[0],lo[1],lo[2],lo[3]);
  *(ushort4*)&xl[i+4] = make_ushort4(lo[4],lo[5],lo[6],lo[7]);
}

// ---- transpose + split W1 (f32 [k][n]) -> W1t hi/lo (bf16 [n][k])
__global__ void k_tw1(const float* __restrict__ W1, u16* __restrict__ wh, u16* __restrict__ wl){
  int id = blockIdx.x*256 + threadIdx.x;    // 65536 total
  int n = id & 255, k = id >> 8;
  float v = W1[k*F1 + n];
  u16 h = f2bf(v);
  wh[n*FIN + k] = h;
  wl[n*FIN + k] = f2bf(v - us2f(h));
}

// ---- GEMM1 (MFMA bf16x3) + fused attention dots.
// Block: 64 rows x 256 cols, 4 waves; wave w: 64 rows x 64 cols (head w).
// Per K-step: 16 VMEM loads vs 48 MFMA (3:1) — was 34:48.
__global__ __launch_bounds__(256) void k_gemm1(const short* __restrict__ xh, const short* __restrict__ xl,
                                               const short* __restrict__ wh, const short* __restrict__ wl,
                                               const float* __restrict__ as1, const float* __restrict__ ad1,
                                               u16* __restrict__ h1b,
                                               float* __restrict__ aS, float* __restrict__ aD){
  int w = threadIdx.x >> 6, lane = threadIdx.x & 63;
  int lo = lane & 15, hi = lane >> 4;
  int rowbase = blockIdx.x*64;
  f32x4 acc[4][4];                       // [rg][tt]
  #pragma unroll
  for(int rg=0;rg<4;rg++)
    #pragma unroll
    for(int tt=0;tt<4;tt++) acc[rg][tt] = (f32x4){0.f,0.f,0.f,0.f};
  // A row for rg: rowbase + rg*16 + lo (clamped); B row (=out col) for tt: w*64 + tt*16 + lo
  size_t aoff[4];
  #pragma unroll
  for(int rg=0;rg<4;rg++){
    int r = rowbase + rg*16 + lo; if(r >= NN) r = NN-1;
    aoff[rg] = (size_t)r*FIN + 8*hi;
  }
  const short* wph = wh + (size_t)(w*64+lo)*FIN + 8*hi;
  const short* wpl = wl + (size_t)(w*64+lo)*FIN + 8*hi;
  for(int k0=0; k0<FIN; k0+=32){
    bf16x8 ah[4], al[4], bh[4], bl[4];
    #pragma unroll
    for(int rg=0;rg<4;rg++){
      ah[rg] = *(const bf16x8*)(xh + aoff[rg] + k0);
      al[rg] = *(const bf16x8*)(xl + aoff[rg] + k0);
    }
    #pragma unroll
    for(int tt=0;tt<4;tt++){
      bh[tt] = *(const bf16x8*)(wph + (size_t)tt*16*FIN + k0);
      bl[tt] = *(const bf16x8*)(wpl + (size_t)tt*16*FIN + k0);
    }
    #pragma unroll
    for(int rg=0;rg<4;rg++){
      #pragma unroll
      for(int tt=0;tt<4;tt++){
        acc[rg][tt] = __builtin_amdgcn_mfma_f32_16x16x32_bf16(ah[rg], bh[tt], acc[rg][tt], 0, 0, 0);
        acc[rg][tt] = __builtin_amdgcn_mfma_f32_16x16x32_bf16(al[rg], bh[tt], acc[rg][tt], 0, 0, 0);
        acc[rg][tt] = __builtin_amdgcn_mfma_f32_16x16x32_bf16(ah[rg], bl[tt], acc[rg][tt], 0, 0, 0);
      }
    }
  }
  // h1 store (bf16): row = rowbase+rg*16+hi*4+r, col = w*64+tt*16+lo
  #pragma unroll
  for(int rg=0;rg<4;rg++){
    #pragma unroll
    for(int tt=0;tt<4;tt++){
      #pragma unroll
      for(int r=0;r<4;r++){
        int row = rowbase + rg*16 + hi*4 + r;
        if(row < NN) h1b[(size_t)row*F1 + w*64 + tt*16 + lo] = f2bf(acc[rg][tt][r]);
      }
    }
  }
  // fused attention dots for head w (prescaled by log2 e)
  float ps[4][4], pd[4][4];              // [rg][r]
  #pragma unroll
  for(int rg=0;rg<4;rg++)
    #pragma unroll
    for(int r=0;r<4;r++){ ps[rg][r]=0.f; pd[rg][r]=0.f; }
  #pragma unroll
  for(int tt=0;tt<4;tt++){
    float sv = as1[w*64+tt*16+lo]*LOG2E, dv = ad1[w*64+tt*16+lo]*LOG2E;
    #pragma unroll
    for(int rg=0;rg<4;rg++)
      #pragma unroll
      for(int r=0;r<4;r++){ ps[rg][r] += acc[rg][tt][r]*sv; pd[rg][r] += acc[rg][tt][r]*dv; }
  }
  #pragma unroll
  for(int off=1; off<16; off<<=1){
    #pragma unroll
    for(int rg=0;rg<4;rg++)
      #pragma unroll
      for(int r=0;r<4;r++){
        ps[rg][r] += __shfl_xor(ps[rg][r], off, 64);
        pd[rg][r] += __shfl_xor(pd[rg][r], off, 64);
      }
  }
  if(lo == 0){
    #pragma unroll
    for(int rg=0;rg<4;rg++)
      #pragma unroll
      for(int r=0;r<4;r++){
        int row = rowbase + rg*16 + hi*4 + r;
        if(row < NN){ aS[row*HEADS+w] = ps[rg][r]; aD[row*HEADS+w] = pd[rg][r]; }
      }
  }
}

// ---- layer-1 aggregation + bias + BN + ELU -> h2 (f32), one wave per node.
__global__ __launch_bounds__(256) void k_agg1(const u16* __restrict__ h1b,
  const float* __restrict__ aS, const float* __restrict__ aD,
  const int* __restrict__ rowptr, const int* __restrict__ adj,
  const float* __restrict__ b1, const float* __restrict__ g1, const float* __restrict__ be1,
  const float* __restrict__ mn1, const float* __restrict__ vr1,
  float* __restrict__ h2){
  __shared__ float lw[4][CHUNK*4];   // [wave][i*4+head]
  __shared__ int   lsrc[4][CHUNK];
  int w = threadIdx.x >> 6, lane = threadIdx.x & 63;
  int node = blockIdx.x*4 + w;
  int h = lane >> 4;
  int beg = rowptr[node], end = rowptr[node+1];
  float4 ad4 = *(const float4*)&aD[node*HEADS];
  float den[4] = {0.f,0.f,0.f,0.f};
  float a0=0.f, a1=0.f, a2=0.f, a3=0.f;
  int total = end - beg + 1;                  // + self loop
  for(int c0=0; c0<total; c0+=CHUNK){
    int n = min(CHUNK, total - c0);
    for(int i=lane; i<n; i+=64){
      int e = beg + c0 + i;
      int src = (e < end) ? adj[e] : node;
      float4 s4 = *(const float4*)&aS[src*HEADS];
      float w0 = s4.x + ad4.x; w0 = w0>0.f?w0:SLOPE*w0; w0 = exp2f(fminf(w0,110.f));
      float w1 = s4.y + ad4.y; w1 = w1>0.f?w1:SLOPE*w1; w1 = exp2f(fminf(w1,110.f));
      float w2 = s4.z + ad4.z; w2 = w2>0.f?w2:SLOPE*w2; w2 = exp2f(fminf(w2,110.f));
      float w3 = s4.w + ad4.w; w3 = w3>0.f?w3:SLOPE*w3; w3 = exp2f(fminf(w3,110.f));
      lsrc[w][i] = src;
      *(float4*)&lw[w][i*4] = make_float4(w0,w1,w2,w3);
      den[0]+=w0; den[1]+=w1; den[2]+=w2; den[3]+=w3;
    }
    asm volatile("s_waitcnt lgkmcnt(0)" ::: "memory");
    #pragma unroll 2
    for(int i=0;i<n;i++){
      int s = lsrc[w][i];
      float wg = lw[w][i*4+h];
      ushort4 hv = *(const ushort4*)&h1b[(size_t)s*F1 + lane*4];
      a0 += wg*us2f(hv.x); a1 += wg*us2f(hv.y); a2 += wg*us2f(hv.z); a3 += wg*us2f(hv.w);
    }
  }
  #pragma unroll
  for(int off=1; off<64; off<<=1){
    #pragma unroll
    for(int q=0;q<4;q++) den[q] += __shfl_xor(den[q], off, 64);
  }
  float inv = 1.f/(den[h] + 1e-16f);
  int c = lane*4;
  float o[4] = {a0*inv, a1*inv, a2*inv, a3*inv};
  #pragma unroll
  for(int j=0;j<4;j++){
    float v = o[j] + b1[c+j];
    v = (v - mn1[c+j]) * rsqrtf(vr1[c+j] + 1e-5f) * g1[c+j] + be1[c+j];
    v = v > 0.f ? v : (__expf(v) - 1.f);            // ELU
    o[j] = v;
  }
  *(float4*)&h2[(size_t)node*F1 + c] = make_float4(o[0],o[1],o[2],o[3]);
}

// ---- GEMM2 (8 waves/block) + attention dots layer 2 (prescaled)
__global__ __launch_bounds__(512) void k_gemm2(const float* __restrict__ h2, const float* __restrict__ W2,
    const float* __restrict__ as2, const float* __restrict__ ad2,
    float* __restrict__ h2p, float* __restrict__ aS2, float* __restrict__ aD2){
  __shared__ float w2s[F1*NC];          // 40 KB
  __shared__ float sh2[8][F1];          // 8 KB
  for(int i=threadIdx.x; i<F1*NC; i+=512) w2s[i] = W2[i];
  int w = threadIdx.x >> 6, lane = threadIdx.x & 63;
  int node = blockIdx.x*8 + w;
  {
    float4 hv = *(const float4*)&h2[(size_t)node*F1 + lane*4];
    *(float4*)&sh2[w][lane*4] = hv;
  }
  __syncthreads();
  float acc = 0.f;
  if(lane < NC){
    #pragma unroll 8
    for(int k=0; k<F1; k++) acc += sh2[w][k] * w2s[k*NC + lane];
  }
  float av = (lane < NC) ? as2[lane] : 0.f;
  float dv = (lane < NC) ? ad2[lane] : 0.f;
  float ps = acc*av, pd = acc*dv;
  #pragma unroll
  for(int off=1; off<64; off<<=1){ ps += __shfl_xor(ps,off,64); pd += __shfl_xor(pd,off,64); }
  if(lane < NC) h2p[(size_t)node*NC + lane] = acc;
  if(lane == 0){ aS2[node] = ps*LOG2E; aD2[node] = pd*LOG2E; }
}

// ---- layer-2 aggregation -> output (f32), no max pass, LDS weights
__global__ __launch_bounds__(256) void k_agg2(const float* __restrict__ h2p,
  const float* __restrict__ aS2, const float* __restrict__ aD2,
  const int* __restrict__ rowptr, const int* __restrict__ adj,
  const float* __restrict__ b2, float* __restrict__ out){
  __shared__ float lw[4][CHUNK];
  __shared__ int   lsrc[4][CHUNK];
  int w = threadIdx.x >> 6, lane = threadIdx.x & 63;
  int node = blockIdx.x*4 + w;
  int beg = rowptr[node], end = rowptr[node+1];
  float adv = aD2[node];
  float den = 0.f, acc = 0.f;
  int total = end - beg + 1;
  for(int c0=0; c0<total; c0+=CHUNK){
    int n = min(CHUNK, total - c0);
    for(int i=lane; i<n; i+=64){
      int e = beg + c0 + i;
      int src = (e < end) ? adj[e] : node;
      float ev = aS2[src] + adv; ev = ev>0.f?ev:SLOPE*ev;
      float wg = exp2f(fminf(ev,110.f));
      lsrc[w][i] = src;
      lw[w][i] = wg;
      den += wg;
    }
    asm volatile("s_waitcnt lgkmcnt(0)" ::: "memory");
    #pragma unroll 2
    for(int i=0;i<n;i++){
      int s = lsrc[w][i];
      float wg = lw[w][i];
      if(lane < NC) acc += wg * h2p[(size_t)s*NC + lane];
    }
  }
  #pragma unroll
  for(int off=1; off<64; off<<=1) den += __shfl_xor(den, off, 64);
  if(lane < NC) out[(size_t)node*NC + lane] = acc/(den + 1e-16f) + b2[lane];
}

extern "C" void kernel_launch(void* const* d_in, const int* in_sizes, int n_in,
                              void* d_out, int out_size, void* d_ws, size_t ws_size,
                              hipStream_t stream){
  (void)in_sizes; (void)n_in; (void)out_size; (void)ws_size;
  const float* x   = (const float*)d_in[0];
  const int*   ei  = (const int*)d_in[1];
  const float* W1  = (const float*)d_in[2];
  const float* as1 = (const float*)d_in[3];
  const float* ad1 = (const float*)d_in[4];
  const float* b1  = (const float*)d_in[5];
  const float* g1  = (const float*)d_in[6];
  const float* be1 = (const float*)d_in[7];
  const float* mn1 = (const float*)d_in[8];
  const float* vr1 = (const float*)d_in[9];
  const float* W2  = (const float*)d_in[10];
  const float* as2 = (const float*)d_in[11];
  const float* ad2 = (const float*)d_in[12];
  const float* b2  = (const float*)d_in[13];

  char* ws = (char*)d_ws;
  u16*  h1b    = (u16*) (ws + 0);             // 25,600,000 (bf16 h1)
  float* h2    = (float*)(ws + 25600000);     // 51,200,000
  // xh/xl alias h2 (dead once k_gemm1 completes; h2 written later by k_agg1)
  u16*  xh     = (u16*) (ws + 25600000);      // 25,600,000
  u16*  xl     = (u16*) (ws + 51200000);      // 25,600,000
  // w1h/w1l alias h2p (dead before k_gemm2 writes h2p)
  float* h2p   = (float*)(ws + 76800000);     //  8,000,000
  u16*  w1h    = (u16*) (ws + 76800000);      //    131,072
  u16*  w1l    = (u16*) (ws + 76931072);      //    131,072
  float* aS1   = (float*)(ws + 84800000);     //    800,000
  float* aD1   = (float*)(ws + 85600000);     //    800,000
  float* aS2   = (float*)(ws + 86400000);     //    200,000
  float* aD2   = (float*)(ws + 86600000);     //    200,000
  int*  rowptr = (int*)  (ws + 86800000);     //    200,016
  int*  rowfill= (int*)  (ws + 87000016);     //    200,000
  int*  adj    = (int*)  (ws + 87200016);     //  6,400,000
  int*  flags  = (int*)  (ws + 93600016);     //         16

  hipMemsetAsync(rowfill, 0, NN*sizeof(int), stream);
  k_detect<<<1, 256, 0, stream>>>(ei, flags);
  k_count <<<(NE+255)/256, 256, 0, stream>>>(ei, flags, rowfill);
  k_scan  <<<1, 1024, 0, stream>>>(rowfill, rowptr);
  k_fill  <<<(NE+255)/256, 256, 0, stream>>>(ei, flags, rowfill, adj);
  k_tw1   <<<256, 256, 0, stream>>>(W1, w1h, w1l);
  k_splitx<<<NN*FIN/8/256, 256, 0, stream>>>(x, xh, xl);
  k_gemm1 <<<(NN+63)/64, 256, 0, stream>>>((const short*)xh, (const short*)xl,
                                           (const short*)w1h, (const short*)w1l,
                                           as1, ad1, h1b, aS1, aD1);
  k_agg1  <<<NN/4, 256, 0, stream>>>(h1b, aS1, aD1, rowptr, adj, b1, g1, be1, mn1, vr1, h2);
  k_gemm2 <<<NN/8, 512, 0, stream>>>(h2, W2, as2, ad2, h2p, aS2, aD2);
  k_agg2  <<<NN/4, 256, 0, stream>>>(h2p, aS2, aD2, rowptr, adj, b2, (float*)d_out);
}

// Round 7
// 676.081 us; speedup vs baseline: 13.4370x; 1.0551x over previous
//
#include <hip/hip_runtime.h>
#include <hip/hip_bf16.h>

#define NN 50000
#define FIN 256
#define F1 256      // HEADS*HID
#define HEADS 4
#define HID 64
#define NC 40
#define NE 1600000
#define SLOPE 0.2f
#define LOG2E 1.44269504f
#define CHUNK 128
#define NB 391      // dst buckets of 128 nodes
#define NCOL 8      // colors (~XCD via blockIdx round-robin)
#define BCAP 1024   // sub-bucket capacity (mean 511, +22 sigma)

typedef unsigned int u32;
typedef unsigned short u16;
typedef __attribute__((ext_vector_type(8))) short bf16x8;
typedef __attribute__((ext_vector_type(4))) float f32x4;

__device__ __forceinline__ float us2f(u32 u){ u32 b = u << 16; return __uint_as_float(b); }
__device__ __forceinline__ u16 f2bf(float f){
  u32 b = __float_as_uint(f);
  u32 r = (b + 0x7fffu + ((b >> 16) & 1u)) >> 16;
  return (u16)r;
}
__device__ __forceinline__ int ld_src(const int* ei, int i, int i64){ return i64 ? ei[2*i] : ei[i]; }
__device__ __forceinline__ int ld_dst(const int* ei, int i, int i64){ return i64 ? ei[2*(NE+i)] : ei[NE+i]; }

// ---- int-width detection: flags[1]=1 if edge_index is int64 on device
__global__ void k_detect(const int* ei, int* flags){
  __shared__ int ci;
  if(threadIdx.x==0) ci=0;
  __syncthreads();
  if(ei[2*threadIdx.x+1] != 0) atomicAdd(&ci, 1);
  __syncthreads();
  if(threadIdx.x==0){ flags[0] = 0; flags[1] = (ci == 0) ? 1 : 0; }
}

// ---- fused prep: edge binning (blocks 0..6249) + x split (6250..12499) + W1 transpose/split (12500..12755)
__global__ __launch_bounds__(256) void k_prep(const int* __restrict__ ei, const int* __restrict__ flags,
      int* __restrict__ cnt, u32* __restrict__ bin,
      const float* __restrict__ x, u16* __restrict__ xh, u16* __restrict__ xl,
      const float* __restrict__ W1, u16* __restrict__ w1h, u16* __restrict__ w1l){
  int bid = blockIdx.x, tid = threadIdx.x;
  if(bid < 6250){
    // bin edges: append (src | dlocal<<16) to sub-bucket [dst>>7][bid&7]
    int i64 = flags[1];
    int i = bid*256 + tid;                        // NE == 6250*256 exactly
    int src = ld_src(ei,i,i64), dst = ld_dst(ei,i,i64);
    int b = dst >> 7;
    int sub = b*NCOL + (bid & (NCOL-1));
    int pos = atomicAdd(&cnt[sub], 1);
    if(pos < BCAP) bin[(size_t)sub*BCAP + pos] = (u32)src | ((u32)(dst & 127) << 16);
  } else if(bid < 12500){
    // split x (f32) -> xh + xl (bf16 each), 8 elems/thread
    int i = ((bid-6250)*256 + tid) * 8;
    float4 a = *(const float4*)(x+i);
    float4 b4 = *(const float4*)(x+i+4);
    float v[8] = {a.x,a.y,a.z,a.w,b4.x,b4.y,b4.z,b4.w};
    u16 hi[8], lo[8];
    #pragma unroll
    for(int j=0;j<8;j++){
      u32 u = __float_as_uint(v[j]);
      hi[j] = (u16)(u >> 16);                      // truncate hi
      float hf = __uint_as_float(u & 0xffff0000u);
      lo[j] = (u16)(__float_as_uint(v[j] - hf) >> 16);
    }
    *(ushort4*)&xh[i]   = make_ushort4(hi[0],hi[1],hi[2],hi[3]);
    *(ushort4*)&xh[i+4] = make_ushort4(hi[4],hi[5],hi[6],hi[7]);
    *(ushort4*)&xl[i]   = make_ushort4(lo[0],lo[1],lo[2],lo[3]);
    *(ushort4*)&xl[i+4] = make_ushort4(lo[4],lo[5],lo[6],lo[7]);
  } else {
    // transpose + split W1 (f32 [k][n]) -> bf16 hi/lo [n][k]
    int id = (bid-12500)*256 + tid;               // 65536 total
    int n = id & 255, k = id >> 8;
    float v = W1[k*F1 + n];
    u16 h = f2bf(v);
    w1h[n*FIN + k] = h;
    w1l[n*FIN + k] = f2bf(v - us2f(h));
  }
}

// ---- per-bucket degree histogram (dense bin reads, LDS atomics)
__global__ __launch_bounds__(256) void k_hist(const int* __restrict__ cnt, const u32* __restrict__ bin,
                                              int* __restrict__ deg){
  __shared__ int dl[128];
  int b = blockIdx.x, tid = threadIdx.x;
  if(tid < 128) dl[tid] = 0;
  __syncthreads();
  for(int s=0;s<NCOL;s++){
    int n = min(cnt[b*NCOL+s], BCAP);
    const u32* bp = bin + (size_t)(b*NCOL+s)*BCAP;
    for(int i=tid;i<n;i+=256) atomicAdd(&dl[bp[i]>>16], 1);
  }
  __syncthreads();
  int d = b*128 + tid;
  if(tid < 128 && d < NN) deg[d] = dl[tid];
}

__global__ __launch_bounds__(1024) void k_scan(int* __restrict__ degfill, int* __restrict__ rowptr){
  __shared__ int sums[1024];
  int t = threadIdx.x;
  const int C = (NN + 1023) / 1024;
  int base = t * C, s = 0;
  for(int j=0;j<C;j++){ int idx=base+j; if(idx<NN) s += degfill[idx]; }
  sums[t] = s; __syncthreads();
  for(int off=1; off<1024; off<<=1){
    int v = (t >= off) ? sums[t-off] : 0;
    __syncthreads();
    sums[t] += v;
    __syncthreads();
  }
  int run = (t==0) ? 0 : sums[t-1];
  for(int j=0;j<C;j++){
    int idx = base + j;
    if(idx < NN){ int d = degfill[idx]; rowptr[idx] = run; degfill[idx] = run; run += d; }
  }
  if(t==1023) rowptr[NN] = run;
}

// ---- per-bucket scatter into contiguous adj window (LDS cursors)
__global__ __launch_bounds__(256) void k_fill2(const int* __restrict__ cnt, const u32* __restrict__ bin,
                                               const int* __restrict__ rowptr, int* __restrict__ adj){
  __shared__ int cur[128];
  int b = blockIdx.x, tid = threadIdx.x;
  if(tid < 128){
    int d = b*128 + tid;
    cur[tid] = (d < NN) ? rowptr[d] : 0;
  }
  __syncthreads();
  for(int s=0;s<NCOL;s++){
    int n = min(cnt[b*NCOL+s], BCAP);
    const u32* bp = bin + (size_t)(b*NCOL+s)*BCAP;
    for(int i=tid;i<n;i+=256){
      u32 v = bp[i];
      int p = atomicAdd(&cur[v>>16], 1);
      adj[p] = (int)(v & 0xffffu);
    }
  }
}

// ---- GEMM1 (MFMA bf16x3) + fused attention dots.
// Block: 64 rows x 256 cols, 4 waves; wave w: 64 rows x 64 cols (head w).
__global__ __launch_bounds__(256) void k_gemm1(const short* __restrict__ xh, const short* __restrict__ xl,
                                               const short* __restrict__ wh, const short* __restrict__ wl,
                                               const float* __restrict__ as1, const float* __restrict__ ad1,
                                               u16* __restrict__ h1b,
                                               float* __restrict__ aS, float* __restrict__ aD){
  int w = threadIdx.x >> 6, lane = threadIdx.x & 63;
  int lo = lane & 15, hi = lane >> 4;
  int rowbase = blockIdx.x*64;
  f32x4 acc[4][4];                       // [rg][tt]
  #pragma unroll
  for(int rg=0;rg<4;rg++)
    #pragma unroll
    for(int tt=0;tt<4;tt++) acc[rg][tt] = (f32x4){0.f,0.f,0.f,0.f};
  size_t aoff[4];
  #pragma unroll
  for(int rg=0;rg<4;rg++){
    int r = rowbase + rg*16 + lo; if(r >= NN) r = NN-1;
    aoff[rg] = (size_t)r*FIN + 8*hi;
  }
  const short* wph = wh + (size_t)(w*64+lo)*FIN + 8*hi;
  const short* wpl = wl + (size_t)(w*64+lo)*FIN + 8*hi;
  for(int k0=0; k0<FIN; k0+=32){
    bf16x8 ah[4], al[4], bh[4], bl[4];
    #pragma unroll
    for(int rg=0;rg<4;rg++){
      ah[rg] = *(const bf16x8*)(xh + aoff[rg] + k0);
      al[rg] = *(const bf16x8*)(xl + aoff[rg] + k0);
    }
    #pragma unroll
    for(int tt=0;tt<4;tt++){
      bh[tt] = *(const bf16x8*)(wph + (size_t)tt*16*FIN + k0);
      bl[tt] = *(const bf16x8*)(wpl + (size_t)tt*16*FIN + k0);
    }
    #pragma unroll
    for(int rg=0;rg<4;rg++){
      #pragma unroll
      for(int tt=0;tt<4;tt++){
        acc[rg][tt] = __builtin_amdgcn_mfma_f32_16x16x32_bf16(ah[rg], bh[tt], acc[rg][tt], 0, 0, 0);
        acc[rg][tt] = __builtin_amdgcn_mfma_f32_16x16x32_bf16(al[rg], bh[tt], acc[rg][tt], 0, 0, 0);
        acc[rg][tt] = __builtin_amdgcn_mfma_f32_16x16x32_bf16(ah[rg], bl[tt], acc[rg][tt], 0, 0, 0);
      }
    }
  }
  #pragma unroll
  for(int rg=0;rg<4;rg++){
    #pragma unroll
    for(int tt=0;tt<4;tt++){
      #pragma unroll
      for(int r=0;r<4;r++){
        int row = rowbase + rg*16 + hi*4 + r;
        if(row < NN) h1b[(size_t)row*F1 + w*64 + tt*16 + lo] = f2bf(acc[rg][tt][r]);
      }
    }
  }
  // fused attention dots for head w (prescaled by log2 e)
  float ps[4][4], pd[4][4];              // [rg][r]
  #pragma unroll
  for(int rg=0;rg<4;rg++)
    #pragma unroll
    for(int r=0;r<4;r++){ ps[rg][r]=0.f; pd[rg][r]=0.f; }
  #pragma unroll
  for(int tt=0;tt<4;tt++){
    float sv = as1[w*64+tt*16+lo]*LOG2E, dv = ad1[w*64+tt*16+lo]*LOG2E;
    #pragma unroll
    for(int rg=0;rg<4;rg++)
      #pragma unroll
      for(int r=0;r<4;r++){ ps[rg][r] += acc[rg][tt][r]*sv; pd[rg][r] += acc[rg][tt][r]*dv; }
  }
  #pragma unroll
  for(int off=1; off<16; off<<=1){
    #pragma unroll
    for(int rg=0;rg<4;rg++)
      #pragma unroll
      for(int r=0;r<4;r++){
        ps[rg][r] += __shfl_xor(ps[rg][r], off, 64);
        pd[rg][r] += __shfl_xor(pd[rg][r], off, 64);
      }
  }
  if(lo == 0){
    #pragma unroll
    for(int rg=0;rg<4;rg++)
      #pragma unroll
      for(int r=0;r<4;r++){
        int row = rowbase + rg*16 + hi*4 + r;
        if(row < NN){ aS[row*HEADS+w] = ps[rg][r]; aD[row*HEADS+w] = pd[rg][r]; }
      }
  }
}

// ---- layer-1 aggregation + bias + BN + ELU -> h2 (f32), one wave per node.
__global__ __launch_bounds__(256) void k_agg1(const u16* __restrict__ h1b,
  const float* __restrict__ aS, const float* __restrict__ aD,
  const int* __restrict__ rowptr, const int* __restrict__ adj,
  const float* __restrict__ b1, const float* __restrict__ g1, const float* __restrict__ be1,
  const float* __restrict__ mn1, const float* __restrict__ vr1,
  float* __restrict__ h2){
  __shared__ float lw[4][CHUNK*4];   // [wave][i*4+head]
  __shared__ int   lsrc[4][CHUNK];
  int w = threadIdx.x >> 6, lane = threadIdx.x & 63;
  int node = blockIdx.x*4 + w;
  int h = lane >> 4;
  int beg = rowptr[node], end = rowptr[node+1];
  float4 ad4 = *(const float4*)&aD[node*HEADS];
  float den[4] = {0.f,0.f,0.f,0.f};
  float a0=0.f, a1=0.f, a2=0.f, a3=0.f;
  int total = end - beg + 1;                  // + self loop
  for(int c0=0; c0<total; c0+=CHUNK){
    int n = min(CHUNK, total - c0);
    for(int i=lane; i<n; i+=64){
      int e = beg + c0 + i;
      int src = (e < end) ? adj[e] : node;
      float4 s4 = *(const float4*)&aS[src*HEADS];
      float w0 = s4.x + ad4.x; w0 = w0>0.f?w0:SLOPE*w0; w0 = exp2f(fminf(w0,110.f));
      float w1 = s4.y + ad4.y; w1 = w1>0.f?w1:SLOPE*w1; w1 = exp2f(fminf(w1,110.f));
      float w2 = s4.z + ad4.z; w2 = w2>0.f?w2:SLOPE*w2; w2 = exp2f(fminf(w2,110.f));
      float w3 = s4.w + ad4.w; w3 = w3>0.f?w3:SLOPE*w3; w3 = exp2f(fminf(w3,110.f));
      lsrc[w][i] = src;
      *(float4*)&lw[w][i*4] = make_float4(w0,w1,w2,w3);
      den[0]+=w0; den[1]+=w1; den[2]+=w2; den[3]+=w3;
    }
    asm volatile("s_waitcnt lgkmcnt(0)" ::: "memory");
    #pragma unroll 2
    for(int i=0;i<n;i++){
      int s = lsrc[w][i];
      float wg = lw[w][i*4+h];
      ushort4 hv = *(const ushort4*)&h1b[(size_t)s*F1 + lane*4];
      a0 += wg*us2f(hv.x); a1 += wg*us2f(hv.y); a2 += wg*us2f(hv.z); a3 += wg*us2f(hv.w);
    }
  }
  #pragma unroll
  for(int off=1; off<64; off<<=1){
    #pragma unroll
    for(int q=0;q<4;q++) den[q] += __shfl_xor(den[q], off, 64);
  }
  float inv = 1.f/(den[h] + 1e-16f);
  int c = lane*4;
  float o[4] = {a0*inv, a1*inv, a2*inv, a3*inv};
  #pragma unroll
  for(int j=0;j<4;j++){
    float v = o[j] + b1[c+j];
    v = (v - mn1[c+j]) * rsqrtf(vr1[c+j] + 1e-5f) * g1[c+j] + be1[c+j];
    v = v > 0.f ? v : (__expf(v) - 1.f);            // ELU
    o[j] = v;
  }
  *(float4*)&h2[(size_t)node*F1 + c] = make_float4(o[0],o[1],o[2],o[3]);
}

// ---- GEMM2 (8 waves/block) + attention dots layer 2 (prescaled)
__global__ __launch_bounds__(512) void k_gemm2(const float* __restrict__ h2, const float* __restrict__ W2,
    const float* __restrict__ as2, const float* __restrict__ ad2,
    float* __restrict__ h2p, float* __restrict__ aS2, float* __restrict__ aD2){
  __shared__ float w2s[F1*NC];          // 40 KB
  __shared__ float sh2[8][F1];          // 8 KB
  for(int i=threadIdx.x; i<F1*NC; i+=512) w2s[i] = W2[i];
  int w = threadIdx.x >> 6, lane = threadIdx.x & 63;
  int node = blockIdx.x*8 + w;
  {
    float4 hv = *(const float4*)&h2[(size_t)node*F1 + lane*4];
    *(float4*)&sh2[w][lane*4] = hv;
  }
  __syncthreads();
  float acc = 0.f;
  if(lane < NC){
    #pragma unroll 8
    for(int k=0; k<F1; k++) acc += sh2[w][k] * w2s[k*NC + lane];
  }
  float av = (lane < NC) ? as2[lane] : 0.f;
  float dv = (lane < NC) ? ad2[lane] : 0.f;
  float ps = acc*av, pd = acc*dv;
  #pragma unroll
  for(int off=1; off<64; off<<=1){ ps += __shfl_xor(ps,off,64); pd += __shfl_xor(pd,off,64); }
  if(lane < NC) h2p[(size_t)node*NC + lane] = acc;
  if(lane == 0){ aS2[node] = ps*LOG2E; aD2[node] = pd*LOG2E; }
}

// ---- layer-2 aggregation -> output (f32), no max pass, LDS weights
__global__ __launch_bounds__(256) void k_agg2(const float* __restrict__ h2p,
  const float* __restrict__ aS2, const float* __restrict__ aD2,
  const int* __restrict__ rowptr, const int* __restrict__ adj,
  const float* __restrict__ b2, float* __restrict__ out){
  __shared__ float lw[4][CHUNK];
  __shared__ int   lsrc[4][CHUNK];
  int w = threadIdx.x >> 6, lane = threadIdx.x & 63;
  int node = blockIdx.x*4 + w;
  int beg = rowptr[node], end = rowptr[node+1];
  float adv = aD2[node];
  float den = 0.f, acc = 0.f;
  int total = end - beg + 1;
  for(int c0=0; c0<total; c0+=CHUNK){
    int n = min(CHUNK, total - c0);
    for(int i=lane; i<n; i+=64){
      int e = beg + c0 + i;
      int src = (e < end) ? adj[e] : node;
      float ev = aS2[src] + adv; ev = ev>0.f?ev:SLOPE*ev;
      float wg = exp2f(fminf(ev,110.f));
      lsrc[w][i] = src;
      lw[w][i] = wg;
      den += wg;
    }
    asm volatile("s_waitcnt lgkmcnt(0)" ::: "memory");
    #pragma unroll 2
    for(int i=0;i<n;i++){
      int s = lsrc[w][i];
      float wg = lw[w][i];
      if(lane < NC) acc += wg * h2p[(size_t)s*NC + lane];
    }
  }
  #pragma unroll
  for(int off=1; off<64; off<<=1) den += __shfl_xor(den, off, 64);
  if(lane < NC) out[(size_t)node*NC + lane] = acc/(den + 1e-16f) + b2[lane];
}

extern "C" void kernel_launch(void* const* d_in, const int* in_sizes, int n_in,
                              void* d_out, int out_size, void* d_ws, size_t ws_size,
                              hipStream_t stream){
  (void)in_sizes; (void)n_in; (void)out_size; (void)ws_size;
  const float* x   = (const float*)d_in[0];
  const int*   ei  = (const int*)d_in[1];
  const float* W1  = (const float*)d_in[2];
  const float* as1 = (const float*)d_in[3];
  const float* ad1 = (const float*)d_in[4];
  const float* b1  = (const float*)d_in[5];
  const float* g1  = (const float*)d_in[6];
  const float* be1 = (const float*)d_in[7];
  const float* mn1 = (const float*)d_in[8];
  const float* vr1 = (const float*)d_in[9];
  const float* W2  = (const float*)d_in[10];
  const float* as2 = (const float*)d_in[11];
  const float* ad2 = (const float*)d_in[12];
  const float* b2  = (const float*)d_in[13];

  char* ws = (char*)d_ws;
  u16*  h1b    = (u16*) (ws + 0);             // 25,600,000 (bf16 h1)
  float* h2    = (float*)(ws + 25600000);     // 51,200,000
  // xh/xl alias h2 (dead once k_gemm1 completes; h2 written later by k_agg1)
  u16*  xh     = (u16*) (ws + 25600000);      // 25,600,000
  u16*  xl     = (u16*) (ws + 51200000);      // 25,600,000
  // w1h/w1l alias h2p (dead before k_gemm2 writes h2p)
  float* h2p   = (float*)(ws + 76800000);     //  8,000,000
  u16*  w1h    = (u16*) (ws + 76800000);      //    131,072
  u16*  w1l    = (u16*) (ws + 76931072);      //    131,072
  float* aS1   = (float*)(ws + 84800000);     //    800,000
  float* aD1   = (float*)(ws + 85600000);     //    800,000
  float* aS2   = (float*)(ws + 86400000);     //    200,000
  float* aD2   = (float*)(ws + 86600000);     //    200,000
  int*  rowptr = (int*)  (ws + 86800000);     //    200,016
  int*  deg    = (int*)  (ws + 87000016);     //    200,000
  int*  adj    = (int*)  (ws + 87200016);     //  6,400,000
  int*  flags  = (int*)  (ws + 93600016);     //         16
  u32*  bin    = (u32*)  (ws + 93700000);     // 12,812,288 (391*8*1024*4)
  int*  cnt    = (int*)  (ws + 106600000);    //     12,512 (391*8*4)

  hipMemsetAsync(cnt, 0, NB*NCOL*sizeof(int), stream);
  k_detect<<<1, 256, 0, stream>>>(ei, flags);
  k_prep  <<<12756, 256, 0, stream>>>(ei, flags, cnt, bin, x, xh, xl, W1, w1h, w1l);
  k_hist  <<<NB, 256, 0, stream>>>(cnt, bin, deg);
  k_scan  <<<1, 1024, 0, stream>>>(deg, rowptr);
  k_fill2 <<<NB, 256, 0, stream>>>(cnt, bin, rowptr, adj);
  k_gemm1 <<<(NN+63)/64, 256, 0, stream>>>((const short*)xh, (const short*)xl,
                                           (const short*)w1h, (const short*)w1l,
                                           as1, ad1, h1b, aS1, aD1);
  k_agg1  <<<NN/4, 256, 0, stream>>>(h1b, aS1, aD1, rowptr, adj, b1, g1, be1, mn1, vr1, h2);
  k_gemm2 <<<NN/8, 512, 0, stream>>>(h2, W2, as2, ad2, h2p, aS2, aD2);
  k_agg2  <<<NN/4, 256, 0, stream>>>(h2p, aS2, aD2, rowptr, adj, b2, (float*)d_out);
}

// Round 8
// 580.444 us; speedup vs baseline: 15.6510x; 1.1648x over previous
//
#include <hip/hip_runtime.h>
#include <hip/hip_bf16.h>

#define NN 50000
#define FIN 256
#define F1 256      // HEADS*HID
#define HEADS 4
#define HID 64
#define NC 40
#define NE 1600000
#define SLOPE 0.2f
#define LOG2E 1.44269504f
#define CHUNK 128
#define NB2 98      // coarse dst buckets (512 nodes each)
#define BSH 9
#define BCAP2 18000 // per-bucket capacity (mean 16327, +13 sigma)
#define TILE 2048   // edges per k_bin block

typedef unsigned int u32;
typedef unsigned short u16;
typedef unsigned char u8;
typedef __attribute__((ext_vector_type(8))) short bf16x8;
typedef __attribute__((ext_vector_type(4))) float f32x4;

__device__ __forceinline__ float us2f(u32 u){ u32 b = u << 16; return __uint_as_float(b); }
__device__ __forceinline__ u16 f2bf(float f){
  u32 b = __float_as_uint(f);
  u32 r = (b + 0x7fffu + ((b >> 16) & 1u)) >> 16;
  return (u16)r;
}
__device__ __forceinline__ int ld_src(const int* ei, int i, int i64){ return i64 ? ei[2*i] : ei[i]; }
__device__ __forceinline__ int ld_dst(const int* ei, int i, int i64){ return i64 ? ei[2*(NE+i)] : ei[NE+i]; }

// ---- int-width detection: flags[1]=1 if edge_index is int64 on device
__global__ void k_detect(const int* ei, int* flags){
  __shared__ int ci;
  if(threadIdx.x==0) ci=0;
  __syncthreads();
  if(ei[2*threadIdx.x+1] != 0) atomicAdd(&ci, 1);
  __syncthreads();
  if(threadIdx.x==0){ flags[0] = 0; flags[1] = (ci == 0) ? 1 : 0; }
}

// ---- streaming prep: x split (blocks 0..6249) + W1 transpose/split (6250..6505)
__global__ __launch_bounds__(256) void k_prep(const float* __restrict__ x, u16* __restrict__ xh, u16* __restrict__ xl,
      const float* __restrict__ W1, u16* __restrict__ w1h, u16* __restrict__ w1l){
  int bid = blockIdx.x, tid = threadIdx.x;
  if(bid < 6250){
    int i = (bid*256 + tid) * 8;
    float4 a = *(const float4*)(x+i);
    float4 b4 = *(const float4*)(x+i+4);
    float v[8] = {a.x,a.y,a.z,a.w,b4.x,b4.y,b4.z,b4.w};
    u16 hi[8], lo[8];
    #pragma unroll
    for(int j=0;j<8;j++){
      u32 u = __float_as_uint(v[j]);
      hi[j] = (u16)(u >> 16);                      // truncate hi
      float hf = __uint_as_float(u & 0xffff0000u);
      lo[j] = (u16)(__float_as_uint(v[j] - hf) >> 16);
    }
    *(ushort4*)&xh[i]   = make_ushort4(hi[0],hi[1],hi[2],hi[3]);
    *(ushort4*)&xh[i+4] = make_ushort4(hi[4],hi[5],hi[6],hi[7]);
    *(ushort4*)&xl[i]   = make_ushort4(lo[0],lo[1],lo[2],lo[3]);
    *(ushort4*)&xl[i+4] = make_ushort4(lo[4],lo[5],lo[6],lo[7]);
  } else {
    int id = (bid-6250)*256 + tid;               // 65536 total
    int n = id & 255, k = id >> 8;
    float v = W1[k*F1 + n];
    u16 h = f2bf(v);
    w1h[n*FIN + k] = h;
    w1l[n*FIN + k] = f2bf(v - us2f(h));
  }
}

// ---- LDS-staged edge binning: dense line-granular bucket appends
__global__ __launch_bounds__(256) void k_bin(const int* __restrict__ ei, const int* __restrict__ flags,
                                             int* __restrict__ cnt, u32* __restrict__ bin){
  __shared__ int hcnt[NB2], hoff[NB2], gbase[NB2], hcur[NB2];
  __shared__ u32 staged[TILE];
  __shared__ u8  sbk[TILE];
  int i64 = flags[1];
  int tid = threadIdx.x;
  int e0 = blockIdx.x * TILE;
  int nn = min(TILE, NE - e0);
  for(int b=tid;b<NB2;b+=256) hcnt[b] = 0;
  __syncthreads();
  u32 val[TILE/256]; int bk[TILE/256];
  #pragma unroll
  for(int j=0;j<TILE/256;j++){
    int t = tid + j*256;
    if(t < nn){
      int i = e0 + t;
      int src = ld_src(ei,i,i64), dst = ld_dst(ei,i,i64);
      bk[j] = dst >> BSH;
      val[j] = (u32)src | ((u32)(dst & 511) << 16);
      atomicAdd(&hcnt[bk[j]], 1);
    } else bk[j] = -1;
  }
  __syncthreads();
  if(tid == 0){
    int run = 0;
    for(int b=0;b<NB2;b++){ hoff[b] = run; hcur[b] = run; run += hcnt[b]; }
  }
  __syncthreads();
  if(tid < NB2 && hcnt[tid] > 0) gbase[tid] = atomicAdd(&cnt[tid], hcnt[tid]);
  __syncthreads();
  #pragma unroll
  for(int j=0;j<TILE/256;j++){
    if(bk[j] >= 0){
      int pos = atomicAdd(&hcur[bk[j]], 1);
      staged[pos] = val[j];
      sbk[pos] = (u8)bk[j];
    }
  }
  __syncthreads();
  for(int s=tid; s<nn; s+=256){
    int b = sbk[s];
    int local = gbase[b] + (s - hoff[b]);
    if(local < BCAP2) bin[(size_t)b*BCAP2 + local] = staged[s];
  }
}

// ---- per-bucket degree histogram (dense bin reads, LDS atomics)
__global__ __launch_bounds__(256) void k_hist(const int* __restrict__ cnt, const u32* __restrict__ bin,
                                              int* __restrict__ deg){
  __shared__ int dl[512];
  int b = blockIdx.x, tid = threadIdx.x;
  for(int i=tid;i<512;i+=256) dl[i] = 0;
  __syncthreads();
  int n = min(cnt[b], BCAP2);
  const u32* bp = bin + (size_t)b*BCAP2;
  for(int i=tid;i<n;i+=256) atomicAdd(&dl[(bp[i]>>16)&511], 1);
  __syncthreads();
  for(int i=tid;i<512;i+=256){
    int d = b*512 + i;
    if(d < NN) deg[d] = dl[i];
  }
}

__global__ __launch_bounds__(1024) void k_scan(int* __restrict__ degfill, int* __restrict__ rowptr){
  __shared__ int sums[1024];
  int t = threadIdx.x;
  const int C = (NN + 1023) / 1024;
  int base = t * C, s = 0;
  for(int j=0;j<C;j++){ int idx=base+j; if(idx<NN) s += degfill[idx]; }
  sums[t] = s; __syncthreads();
  for(int off=1; off<1024; off<<=1){
    int v = (t >= off) ? sums[t-off] : 0;
    __syncthreads();
    sums[t] += v;
    __syncthreads();
  }
  int run = (t==0) ? 0 : sums[t-1];
  for(int j=0;j<C;j++){
    int idx = base + j;
    if(idx < NN){ int d = degfill[idx]; rowptr[idx] = run; degfill[idx] = run; run += d; }
  }
  if(t==1023) rowptr[NN] = run;
}

// ---- per-bucket scatter into contiguous adj window (LDS cursors, L2-resident)
__global__ __launch_bounds__(256) void k_fill2(const int* __restrict__ cnt, const u32* __restrict__ bin,
                                               const int* __restrict__ rowptr, int* __restrict__ adj){
  __shared__ int cur[512];
  int b = blockIdx.x, tid = threadIdx.x;
  for(int i=tid;i<512;i+=256){
    int d = b*512 + i;
    cur[i] = (d < NN) ? rowptr[d] : 0;
  }
  __syncthreads();
  int n = min(cnt[b], BCAP2);
  const u32* bp = bin + (size_t)b*BCAP2;
  for(int i=tid;i<n;i+=256){
    u32 v = bp[i];
    int p = atomicAdd(&cur[(v>>16)&511], 1);
    adj[p] = (int)(v & 0xffffu);
  }
}

// ---- GEMM1 (MFMA bf16x3) + fused attention dots.
// Block: 64 rows x 256 cols, 4 waves; wave w: 64 rows x 64 cols (head w).
__global__ __launch_bounds__(256) void k_gemm1(const short* __restrict__ xh, const short* __restrict__ xl,
                                               const short* __restrict__ wh, const short* __restrict__ wl,
                                               const float* __restrict__ as1, const float* __restrict__ ad1,
                                               u16* __restrict__ h1b,
                                               float* __restrict__ aS, float* __restrict__ aD){
  int w = threadIdx.x >> 6, lane = threadIdx.x & 63;
  int lo = lane & 15, hi = lane >> 4;
  int rowbase = blockIdx.x*64;
  f32x4 acc[4][4];                       // [rg][tt]
  #pragma unroll
  for(int rg=0;rg<4;rg++)
    #pragma unroll
    for(int tt=0;tt<4;tt++) acc[rg][tt] = (f32x4){0.f,0.f,0.f,0.f};
  size_t aoff[4];
  #pragma unroll
  for(int rg=0;rg<4;rg++){
    int r = rowbase + rg*16 + lo; if(r >= NN) r = NN-1;
    aoff[rg] = (size_t)r*FIN + 8*hi;
  }
  const short* wph = wh + (size_t)(w*64+lo)*FIN + 8*hi;
  const short* wpl = wl + (size_t)(w*64+lo)*FIN + 8*hi;
  for(int k0=0; k0<FIN; k0+=32){
    bf16x8 ah[4], al[4], bh[4], bl[4];
    #pragma unroll
    for(int rg=0;rg<4;rg++){
      ah[rg] = *(const bf16x8*)(xh + aoff[rg] + k0);
      al[rg] = *(const bf16x8*)(xl + aoff[rg] + k0);
    }
    #pragma unroll
    for(int tt=0;tt<4;tt++){
      bh[tt] = *(const bf16x8*)(wph + (size_t)tt*16*FIN + k0);
      bl[tt] = *(const bf16x8*)(wpl + (size_t)tt*16*FIN + k0);
    }
    #pragma unroll
    for(int rg=0;rg<4;rg++){
      #pragma unroll
      for(int tt=0;tt<4;tt++){
        acc[rg][tt] = __builtin_amdgcn_mfma_f32_16x16x32_bf16(ah[rg], bh[tt], acc[rg][tt], 0, 0, 0);
        acc[rg][tt] = __builtin_amdgcn_mfma_f32_16x16x32_bf16(al[rg], bh[tt], acc[rg][tt], 0, 0, 0);
        acc[rg][tt] = __builtin_amdgcn_mfma_f32_16x16x32_bf16(ah[rg], bl[tt], acc[rg][tt], 0, 0, 0);
      }
    }
  }
  #pragma unroll
  for(int rg=0;rg<4;rg++){
    #pragma unroll
    for(int tt=0;tt<4;tt++){
      #pragma unroll
      for(int r=0;r<4;r++){
        int row = rowbase + rg*16 + hi*4 + r;
        if(row < NN) h1b[(size_t)row*F1 + w*64 + tt*16 + lo] = f2bf(acc[rg][tt][r]);
      }
    }
  }
  // fused attention dots for head w (prescaled by log2 e)
  float ps[4][4], pd[4][4];              // [rg][r]
  #pragma unroll
  for(int rg=0;rg<4;rg++)
    #pragma unroll
    for(int r=0;r<4;r++){ ps[rg][r]=0.f; pd[rg][r]=0.f; }
  #pragma unroll
  for(int tt=0;tt<4;tt++){
    float sv = as1[w*64+tt*16+lo]*LOG2E, dv = ad1[w*64+tt*16+lo]*LOG2E;
    #pragma unroll
    for(int rg=0;rg<4;rg++)
      #pragma unroll
      for(int r=0;r<4;r++){ ps[rg][r] += acc[rg][tt][r]*sv; pd[rg][r] += acc[rg][tt][r]*dv; }
  }
  #pragma unroll
  for(int off=1; off<16; off<<=1){
    #pragma unroll
    for(int rg=0;rg<4;rg++)
      #pragma unroll
      for(int r=0;r<4;r++){
        ps[rg][r] += __shfl_xor(ps[rg][r], off, 64);
        pd[rg][r] += __shfl_xor(pd[rg][r], off, 64);
      }
  }
  if(lo == 0){
    #pragma unroll
    for(int rg=0;rg<4;rg++)
      #pragma unroll
      for(int r=0;r<4;r++){
        int row = rowbase + rg*16 + hi*4 + r;
        if(row < NN){ aS[row*HEADS+w] = ps[rg][r]; aD[row*HEADS+w] = pd[rg][r]; }
      }
  }
}

// ---- layer-1 aggregation + bias + BN + ELU -> h2 (f32), one wave per node.
__global__ __launch_bounds__(256) void k_agg1(const u16* __restrict__ h1b,
  const float* __restrict__ aS, const float* __restrict__ aD,
  const int* __restrict__ rowptr, const int* __restrict__ adj,
  const float* __restrict__ b1, const float* __restrict__ g1, const float* __restrict__ be1,
  const float* __restrict__ mn1, const float* __restrict__ vr1,
  float* __restrict__ h2){
  __shared__ float lw[4][CHUNK*4];   // [wave][i*4+head]
  __shared__ int   lsrc[4][CHUNK];
  int w = threadIdx.x >> 6, lane = threadIdx.x & 63;
  int node = blockIdx.x*4 + w;
  int h = lane >> 4;
  int beg = rowptr[node], end = rowptr[node+1];
  float4 ad4 = *(const float4*)&aD[node*HEADS];
  float den[4] = {0.f,0.f,0.f,0.f};
  float a0=0.f, a1=0.f, a2=0.f, a3=0.f;
  int total = end - beg + 1;                  // + self loop
  for(int c0=0; c0<total; c0+=CHUNK){
    int n = min(CHUNK, total - c0);
    for(int i=lane; i<n; i+=64){
      int e = beg + c0 + i;
      int src = (e < end) ? adj[e] : node;
      float4 s4 = *(const float4*)&aS[src*HEADS];
      float w0 = s4.x + ad4.x; w0 = w0>0.f?w0:SLOPE*w0; w0 = exp2f(fminf(w0,110.f));
      float w1 = s4.y + ad4.y; w1 = w1>0.f?w1:SLOPE*w1; w1 = exp2f(fminf(w1,110.f));
      float w2 = s4.z + ad4.z; w2 = w2>0.f?w2:SLOPE*w2; w2 = exp2f(fminf(w2,110.f));
      float w3 = s4.w + ad4.w; w3 = w3>0.f?w3:SLOPE*w3; w3 = exp2f(fminf(w3,110.f));
      lsrc[w][i] = src;
      *(float4*)&lw[w][i*4] = make_float4(w0,w1,w2,w3);
      den[0]+=w0; den[1]+=w1; den[2]+=w2; den[3]+=w3;
    }
    asm volatile("s_waitcnt lgkmcnt(0)" ::: "memory");
    #pragma unroll 2
    for(int i=0;i<n;i++){
      int s = lsrc[w][i];
      float wg = lw[w][i*4+h];
      ushort4 hv = *(const ushort4*)&h1b[(size_t)s*F1 + lane*4];
      a0 += wg*us2f(hv.x); a1 += wg*us2f(hv.y); a2 += wg*us2f(hv.z); a3 += wg*us2f(hv.w);
    }
  }
  #pragma unroll
  for(int off=1; off<64; off<<=1){
    #pragma unroll
    for(int q=0;q<4;q++) den[q] += __shfl_xor(den[q], off, 64);
  }
  float inv = 1.f/(den[h] + 1e-16f);
  int c = lane*4;
  float o[4] = {a0*inv, a1*inv, a2*inv, a3*inv};
  #pragma unroll
  for(int j=0;j<4;j++){
    float v = o[j] + b1[c+j];
    v = (v - mn1[c+j]) * rsqrtf(vr1[c+j] + 1e-5f) * g1[c+j] + be1[c+j];
    v = v > 0.f ? v : (__expf(v) - 1.f);            // ELU
    o[j] = v;
  }
  *(float4*)&h2[(size_t)node*F1 + c] = make_float4(o[0],o[1],o[2],o[3]);
}

// ---- GEMM2 (8 waves/block) + attention dots layer 2 (prescaled)
__global__ __launch_bounds__(512) void k_gemm2(const float* __restrict__ h2, const float* __restrict__ W2,
    const float* __restrict__ as2, const float* __restrict__ ad2,
    float* __restrict__ h2p, float* __restrict__ aS2, float* __restrict__ aD2){
  __shared__ float w2s[F1*NC];          // 40 KB
  __shared__ float sh2[8][F1];          // 8 KB
  for(int i=threadIdx.x; i<F1*NC; i+=512) w2s[i] = W2[i];
  int w = threadIdx.x >> 6, lane = threadIdx.x & 63;
  int node = blockIdx.x*8 + w;
  {
    float4 hv = *(const float4*)&h2[(size_t)node*F1 + lane*4];
    *(float4*)&sh2[w][lane*4] = hv;
  }
  __syncthreads();
  float acc = 0.f;
  if(lane < NC){
    #pragma unroll 8
    for(int k=0; k<F1; k++) acc += sh2[w][k] * w2s[k*NC + lane];
  }
  float av = (lane < NC) ? as2[lane] : 0.f;
  float dv = (lane < NC) ? ad2[lane] : 0.f;
  float ps = acc*av, pd = acc*dv;
  #pragma unroll
  for(int off=1; off<64; off<<=1){ ps += __shfl_xor(ps,off,64); pd += __shfl_xor(pd,off,64); }
  if(lane < NC) h2p[(size_t)node*NC + lane] = acc;
  if(lane == 0){ aS2[node] = ps*LOG2E; aD2[node] = pd*LOG2E; }
}

// ---- layer-2 aggregation -> output (f32), no max pass, LDS weights
__global__ __launch_bounds__(256) void k_agg2(const float* __restrict__ h2p,
  const float* __restrict__ aS2, const float* __restrict__ aD2,
  const int* __restrict__ rowptr, const int* __restrict__ adj,
  const float* __restrict__ b2, float* __restrict__ out){
  __shared__ float lw[4][CHUNK];
  __shared__ int   lsrc[4][CHUNK];
  int w = threadIdx.x >> 6, lane = threadIdx.x & 63;
  int node = blockIdx.x*4 + w;
  int beg = rowptr[node], end = rowptr[node+1];
  float adv = aD2[node];
  float den = 0.f, acc = 0.f;
  int total = end - beg + 1;
  for(int c0=0; c0<total; c0+=CHUNK){
    int n = min(CHUNK, total - c0);
    for(int i=lane; i<n; i+=64){
      int e = beg + c0 + i;
      int src = (e < end) ? adj[e] : node;
      float ev = aS2[src] + adv; ev = ev>0.f?ev:SLOPE*ev;
      float wg = exp2f(fminf(ev,110.f));
      lsrc[w][i] = src;
      lw[w][i] = wg;
      den += wg;
    }
    asm volatile("s_waitcnt lgkmcnt(0)" ::: "memory");
    #pragma unroll 2
    for(int i=0;i<n;i++){
      int s = lsrc[w][i];
      float wg = lw[w][i];
      if(lane < NC) acc += wg * h2p[(size_t)s*NC + lane];
    }
  }
  #pragma unroll
  for(int off=1; off<64; off<<=1) den += __shfl_xor(den, off, 64);
  if(lane < NC) out[(size_t)node*NC + lane] = acc/(den + 1e-16f) + b2[lane];
}

extern "C" void kernel_launch(void* const* d_in, const int* in_sizes, int n_in,
                              void* d_out, int out_size, void* d_ws, size_t ws_size,
                              hipStream_t stream){
  (void)in_sizes; (void)n_in; (void)out_size; (void)ws_size;
  const float* x   = (const float*)d_in[0];
  const int*   ei  = (const int*)d_in[1];
  const float* W1  = (const float*)d_in[2];
  const float* as1 = (const float*)d_in[3];
  const float* ad1 = (const float*)d_in[4];
  const float* b1  = (const float*)d_in[5];
  const float* g1  = (const float*)d_in[6];
  const float* be1 = (const float*)d_in[7];
  const float* mn1 = (const float*)d_in[8];
  const float* vr1 = (const float*)d_in[9];
  const float* W2  = (const float*)d_in[10];
  const float* as2 = (const float*)d_in[11];
  const float* ad2 = (const float*)d_in[12];
  const float* b2  = (const float*)d_in[13];

  char* ws = (char*)d_ws;
  u16*  h1b    = (u16*) (ws + 0);             // 25,600,000 (bf16 h1)
  float* h2    = (float*)(ws + 25600000);     // 51,200,000
  // xh/xl alias h2 (dead once k_gemm1 completes; h2 written later by k_agg1)
  u16*  xh     = (u16*) (ws + 25600000);      // 25,600,000
  u16*  xl     = (u16*) (ws + 51200000);      // 25,600,000
  // w1h/w1l alias h2p (dead before k_gemm2 writes h2p)
  float* h2p   = (float*)(ws + 76800000);     //  8,000,000
  u16*  w1h    = (u16*) (ws + 76800000);      //    131,072
  u16*  w1l    = (u16*) (ws + 76931072);      //    131,072
  float* aS1   = (float*)(ws + 84800000);     //    800,000
  float* aD1   = (float*)(ws + 85600000);     //    800,000
  float* aS2   = (float*)(ws + 86400000);     //    200,000
  float* aD2   = (float*)(ws + 86600000);     //    200,000
  int*  rowptr = (int*)  (ws + 86800000);     //    200,016
  int*  deg    = (int*)  (ws + 87000016);     //    200,000
  int*  adj    = (int*)  (ws + 87200016);     //  6,400,000
  int*  flags  = (int*)  (ws + 93600016);     //         16
  u32*  bin    = (u32*)  (ws + 93700000);     //  7,056,000 (98*18000*4)
  int*  cnt    = (int*)  (ws + 100800000);    //        392 (98*4)

  hipMemsetAsync(cnt, 0, NB2*sizeof(int), stream);
  k_detect<<<1, 256, 0, stream>>>(ei, flags);
  k_prep  <<<6506, 256, 0, stream>>>(x, xh, xl, W1, w1h, w1l);
  k_bin   <<<(NE+TILE-1)/TILE, 256, 0, stream>>>(ei, flags, cnt, bin);
  k_hist  <<<NB2, 256, 0, stream>>>(cnt, bin, deg);
  k_scan  <<<1, 1024, 0, stream>>>(deg, rowptr);
  k_fill2 <<<NB2, 256, 0, stream>>>(cnt, bin, rowptr, adj);
  k_gemm1 <<<(NN+63)/64, 256, 0, stream>>>((const short*)xh, (const short*)xl,
                                           (const short*)w1h, (const short*)w1l,
                                           as1, ad1, h1b, aS1, aD1);
  k_agg1  <<<NN/4, 256, 0, stream>>>(h1b, aS1, aD1, rowptr, adj, b1, g1, be1, mn1, vr1, h2);
  k_gemm2 <<<NN/8, 512, 0, stream>>>(h2, W2, as2, ad2, h2p, aS2, aD2);
  k_agg2  <<<NN/4, 256, 0, stream>>>(h2p, aS2, aD2, rowptr, adj, b2, (float*)d_out);
}

// Round 9
// 461.234 us; speedup vs baseline: 19.6961x; 1.2585x over previous
//
#include <hip/hip_runtime.h>
#include <hip/hip_bf16.h>

#define NN 50000
#define FIN 256
#define F1 256      // HEADS*HID
#define HEADS 4
#define HID 64
#define NC 40
#define NE 1600000
#define SLOPE 0.2f
#define LOG2E 1.44269504f
#define CHUNK 128
#define NB2 98      // coarse dst buckets (512 nodes each)
#define BSH 9
#define BCAP2 18000 // per-bucket capacity (mean 16327, +13 sigma)
#define TILE 2048   // edges per k_bin block

typedef unsigned int u32;
typedef unsigned short u16;
typedef unsigned char u8;
typedef __attribute__((ext_vector_type(8))) short bf16x8;
typedef __attribute__((ext_vector_type(4))) float f32x4;

__device__ __forceinline__ float us2f(u32 u){ u32 b = u << 16; return __uint_as_float(b); }
__device__ __forceinline__ u16 f2bf(float f){
  u32 b = __float_as_uint(f);
  u32 r = (b + 0x7fffu + ((b >> 16) & 1u)) >> 16;
  return (u16)r;
}
__device__ __forceinline__ int ld_src(const int* ei, int i, int i64){ return i64 ? ei[2*i] : ei[i]; }
__device__ __forceinline__ int ld_dst(const int* ei, int i, int i64){ return i64 ? ei[2*(NE+i)] : ei[NE+i]; }

// ---- int-width detection: flags[1]=1 if edge_index is int64 on device
__global__ void k_detect(const int* ei, int* flags){
  __shared__ int ci;
  if(threadIdx.x==0) ci=0;
  __syncthreads();
  if(ei[2*threadIdx.x+1] != 0) atomicAdd(&ci, 1);
  __syncthreads();
  if(threadIdx.x==0){ flags[0] = 0; flags[1] = (ci == 0) ? 1 : 0; }
}

// ---- streaming prep: x split (blocks 0..6249) + W1 transpose/split (6250..6505)
__global__ __launch_bounds__(256) void k_prep(const float* __restrict__ x, u16* __restrict__ xh, u16* __restrict__ xl,
      const float* __restrict__ W1, u16* __restrict__ w1h, u16* __restrict__ w1l){
  int bid = blockIdx.x, tid = threadIdx.x;
  if(bid < 6250){
    int i = (bid*256 + tid) * 8;
    float4 a = *(const float4*)(x+i);
    float4 b4 = *(const float4*)(x+i+4);
    float v[8] = {a.x,a.y,a.z,a.w,b4.x,b4.y,b4.z,b4.w};
    u16 hi[8], lo[8];
    #pragma unroll
    for(int j=0;j<8;j++){
      u32 u = __float_as_uint(v[j]);
      hi[j] = (u16)(u >> 16);                      // truncate hi
      float hf = __uint_as_float(u & 0xffff0000u);
      lo[j] = (u16)(__float_as_uint(v[j] - hf) >> 16);
    }
    *(ushort4*)&xh[i]   = make_ushort4(hi[0],hi[1],hi[2],hi[3]);
    *(ushort4*)&xh[i+4] = make_ushort4(hi[4],hi[5],hi[6],hi[7]);
    *(ushort4*)&xl[i]   = make_ushort4(lo[0],lo[1],lo[2],lo[3]);
    *(ushort4*)&xl[i+4] = make_ushort4(lo[4],lo[5],lo[6],lo[7]);
  } else {
    int id = (bid-6250)*256 + tid;               // 65536 total
    int n = id & 255, k = id >> 8;
    float v = W1[k*F1 + n];
    u16 h = f2bf(v);
    w1h[n*FIN + k] = h;
    w1l[n*FIN + k] = f2bf(v - us2f(h));
  }
}

// ---- LDS-staged edge binning: dense line-granular bucket appends
__global__ __launch_bounds__(256) void k_bin(const int* __restrict__ ei, const int* __restrict__ flags,
                                             int* __restrict__ cnt, u32* __restrict__ bin){
  __shared__ int hcnt[NB2], hoff[NB2], gbase[NB2], hcur[NB2];
  __shared__ u32 staged[TILE];
  __shared__ u8  sbk[TILE];
  int i64 = flags[1];
  int tid = threadIdx.x;
  int e0 = blockIdx.x * TILE;
  int nn = min(TILE, NE - e0);
  for(int b=tid;b<NB2;b+=256) hcnt[b] = 0;
  __syncthreads();
  u32 val[TILE/256]; int bk[TILE/256];
  #pragma unroll
  for(int j=0;j<TILE/256;j++){
    int t = tid + j*256;
    if(t < nn){
      int i = e0 + t;
      int src = ld_src(ei,i,i64), dst = ld_dst(ei,i,i64);
      bk[j] = dst >> BSH;
      val[j] = (u32)src | ((u32)(dst & 511) << 16);
      atomicAdd(&hcnt[bk[j]], 1);
    } else bk[j] = -1;
  }
  __syncthreads();
  if(tid == 0){
    int run = 0;
    for(int b=0;b<NB2;b++){ hoff[b] = run; hcur[b] = run; run += hcnt[b]; }
  }
  __syncthreads();
  if(tid < NB2 && hcnt[tid] > 0) gbase[tid] = atomicAdd(&cnt[tid], hcnt[tid]);
  __syncthreads();
  #pragma unroll
  for(int j=0;j<TILE/256;j++){
    if(bk[j] >= 0){
      int pos = atomicAdd(&hcur[bk[j]], 1);
      staged[pos] = val[j];
      sbk[pos] = (u8)bk[j];
    }
  }
  __syncthreads();
  for(int s=tid; s<nn; s+=256){
    int b = sbk[s];
    int local = gbase[b] + (s - hoff[b]);
    if(local < BCAP2) bin[(size_t)b*BCAP2 + local] = staged[s];
  }
}

// ---- per-bucket degree histogram + 512-entry LDS exclusive scan
// outputs: rloc[node] = local exclusive offset within bucket, bsum[b] = bucket total
__global__ __launch_bounds__(256) void k_hist(const int* __restrict__ cnt, const u32* __restrict__ bin,
                                              int* __restrict__ rloc, int* __restrict__ bsum){
  __shared__ int dl[512], s1[512], s2[512];
  int b = blockIdx.x, tid = threadIdx.x;
  for(int i=tid;i<512;i+=256) dl[i] = 0;
  __syncthreads();
  int n = min(cnt[b], BCAP2);
  const u32* bp = bin + (size_t)b*BCAP2;
  for(int i=tid;i<n;i+=256) atomicAdd(&dl[(bp[i]>>16)&511], 1);
  __syncthreads();
  for(int i=tid;i<512;i+=256) s1[i] = dl[i];
  __syncthreads();
  int* src = s1; int* dst = s2;
  for(int off=1; off<512; off<<=1){
    for(int i=tid;i<512;i+=256) dst[i] = src[i] + (i>=off ? src[i-off] : 0);
    __syncthreads();
    int* t = src; src = dst; dst = t;
  }
  // src = inclusive scan
  for(int i=tid;i<512;i+=256) rloc[b*512+i] = src[i] - dl[i];
  if(tid==0) bsum[b] = src[511];
}

// ---- tiny serial scan over 98 bucket totals
__global__ void k_scanb(const int* __restrict__ bsum, int* __restrict__ bbase, int* __restrict__ rowptr){
  if(threadIdx.x==0){
    int run = 0;
    for(int b=0;b<NB2;b++){ bbase[b] = run; run += bsum[b]; }
    rowptr[NN] = run;
  }
}

// ---- per-bucket scatter into contiguous adj window; materializes final rowptr
__global__ __launch_bounds__(256) void k_fill2(const int* __restrict__ cnt, const u32* __restrict__ bin,
                                               const int* __restrict__ rloc, const int* __restrict__ bbase,
                                               int* __restrict__ rowptr, int* __restrict__ adj){
  __shared__ int cur[512];
  int b = blockIdx.x, tid = threadIdx.x;
  int base = bbase[b];
  for(int i=tid;i<512;i+=256){
    int d = b*512 + i;
    int v = base + rloc[b*512+i];
    cur[i] = v;
    if(d < NN) rowptr[d] = v;
  }
  __syncthreads();
  int n = min(cnt[b], BCAP2);
  const u32* bp = bin + (size_t)b*BCAP2;
  for(int i=tid;i<n;i+=256){
    u32 v = bp[i];
    int p = atomicAdd(&cur[(v>>16)&511], 1);
    adj[p] = (int)(v & 0xffffu);
  }
}

// ---- GEMM1 (MFMA bf16x3) + fused attention dots.
// Block: 64 rows x 256 cols, 4 waves; wave w: 64 rows x 64 cols (head w).
__global__ __launch_bounds__(256) void k_gemm1(const short* __restrict__ xh, const short* __restrict__ xl,
                                               const short* __restrict__ wh, const short* __restrict__ wl,
                                               const float* __restrict__ as1, const float* __restrict__ ad1,
                                               u16* __restrict__ h1b,
                                               float* __restrict__ aS, float* __restrict__ aD){
  int w = threadIdx.x >> 6, lane = threadIdx.x & 63;
  int lo = lane & 15, hi = lane >> 4;
  int rowbase = blockIdx.x*64;
  f32x4 acc[4][4];                       // [rg][tt]
  #pragma unroll
  for(int rg=0;rg<4;rg++)
    #pragma unroll
    for(int tt=0;tt<4;tt++) acc[rg][tt] = (f32x4){0.f,0.f,0.f,0.f};
  size_t aoff[4];
  #pragma unroll
  for(int rg=0;rg<4;rg++){
    int r = rowbase + rg*16 + lo; if(r >= NN) r = NN-1;
    aoff[rg] = (size_t)r*FIN + 8*hi;
  }
  const short* wph = wh + (size_t)(w*64+lo)*FIN + 8*hi;
  const short* wpl = wl + (size_t)(w*64+lo)*FIN + 8*hi;
  for(int k0=0; k0<FIN; k0+=32){
    bf16x8 ah[4], al[4], bh[4], bl[4];
    #pragma unroll
    for(int rg=0;rg<4;rg++){
      ah[rg] = *(const bf16x8*)(xh + aoff[rg] + k0);
      al[rg] = *(const bf16x8*)(xl + aoff[rg] + k0);
    }
    #pragma unroll
    for(int tt=0;tt<4;tt++){
      bh[tt] = *(const bf16x8*)(wph + (size_t)tt*16*FIN + k0);
      bl[tt] = *(const bf16x8*)(wpl + (size_t)tt*16*FIN + k0);
    }
    #pragma unroll
    for(int rg=0;rg<4;rg++){
      #pragma unroll
      for(int tt=0;tt<4;tt++){
        acc[rg][tt] = __builtin_amdgcn_mfma_f32_16x16x32_bf16(ah[rg], bh[tt], acc[rg][tt], 0, 0, 0);
        acc[rg][tt] = __builtin_amdgcn_mfma_f32_16x16x32_bf16(al[rg], bh[tt], acc[rg][tt], 0, 0, 0);
        acc[rg][tt] = __builtin_amdgcn_mfma_f32_16x16x32_bf16(ah[rg], bl[tt], acc[rg][tt], 0, 0, 0);
      }
    }
  }
  #pragma unroll
  for(int rg=0;rg<4;rg++){
    #pragma unroll
    for(int tt=0;tt<4;tt++){
      #pragma unroll
      for(int r=0;r<4;r++){
        int row = rowbase + rg*16 + hi*4 + r;
        if(row < NN) h1b[(size_t)row*F1 + w*64 + tt*16 + lo] = f2bf(acc[rg][tt][r]);
      }
    }
  }
  // fused attention dots for head w (prescaled by log2 e)
  float ps[4][4], pd[4][4];              // [rg][r]
  #pragma unroll
  for(int rg=0;rg<4;rg++)
    #pragma unroll
    for(int r=0;r<4;r++){ ps[rg][r]=0.f; pd[rg][r]=0.f; }
  #pragma unroll
  for(int tt=0;tt<4;tt++){
    float sv = as1[w*64+tt*16+lo]*LOG2E, dv = ad1[w*64+tt*16+lo]*LOG2E;
    #pragma unroll
    for(int rg=0;rg<4;rg++)
      #pragma unroll
      for(int r=0;r<4;r++){ ps[rg][r] += acc[rg][tt][r]*sv; pd[rg][r] += acc[rg][tt][r]*dv; }
  }
  #pragma unroll
  for(int off=1; off<16; off<<=1){
    #pragma unroll
    for(int rg=0;rg<4;rg++)
      #pragma unroll
      for(int r=0;r<4;r++){
        ps[rg][r] += __shfl_xor(ps[rg][r], off, 64);
        pd[rg][r] += __shfl_xor(pd[rg][r], off, 64);
      }
  }
  if(lo == 0){
    #pragma unroll
    for(int rg=0;rg<4;rg++)
      #pragma unroll
      for(int r=0;r<4;r++){
        int row = rowbase + rg*16 + hi*4 + r;
        if(row < NN){ aS[row*HEADS+w] = ps[rg][r]; aD[row*HEADS+w] = pd[rg][r]; }
      }
  }
}

// ---- layer-1 aggregation + bias + BN + ELU -> h2 (f32), one wave per node.
__global__ __launch_bounds__(256) void k_agg1(const u16* __restrict__ h1b,
  const float* __restrict__ aS, const float* __restrict__ aD,
  const int* __restrict__ rowptr, const int* __restrict__ adj,
  const float* __restrict__ b1, const float* __restrict__ g1, const float* __restrict__ be1,
  const float* __restrict__ mn1, const float* __restrict__ vr1,
  float* __restrict__ h2){
  __shared__ float lw[4][CHUNK*4];   // [wave][i*4+head]
  __shared__ int   lsrc[4][CHUNK];
  int w = threadIdx.x >> 6, lane = threadIdx.x & 63;
  int node = blockIdx.x*4 + w;
  int h = lane >> 4;
  int beg = rowptr[node], end = rowptr[node+1];
  float4 ad4 = *(const float4*)&aD[node*HEADS];
  float den[4] = {0.f,0.f,0.f,0.f};
  float a0=0.f, a1=0.f, a2=0.f, a3=0.f;
  int total = end - beg + 1;                  // + self loop
  for(int c0=0; c0<total; c0+=CHUNK){
    int n = min(CHUNK, total - c0);
    for(int i=lane; i<n; i+=64){
      int e = beg + c0 + i;
      int src = (e < end) ? adj[e] : node;
      float4 s4 = *(const float4*)&aS[src*HEADS];
      float w0 = s4.x + ad4.x; w0 = w0>0.f?w0:SLOPE*w0; w0 = exp2f(fminf(w0,110.f));
      float w1 = s4.y + ad4.y; w1 = w1>0.f?w1:SLOPE*w1; w1 = exp2f(fminf(w1,110.f));
      float w2 = s4.z + ad4.z; w2 = w2>0.f?w2:SLOPE*w2; w2 = exp2f(fminf(w2,110.f));
      float w3 = s4.w + ad4.w; w3 = w3>0.f?w3:SLOPE*w3; w3 = exp2f(fminf(w3,110.f));
      lsrc[w][i] = src;
      *(float4*)&lw[w][i*4] = make_float4(w0,w1,w2,w3);
      den[0]+=w0; den[1]+=w1; den[2]+=w2; den[3]+=w3;
    }
    asm volatile("s_waitcnt lgkmcnt(0)" ::: "memory");
    #pragma unroll 2
    for(int i=0;i<n;i++){
      int s = lsrc[w][i];
      float wg = lw[w][i*4+h];
      ushort4 hv = *(const ushort4*)&h1b[(size_t)s*F1 + lane*4];
      a0 += wg*us2f(hv.x); a1 += wg*us2f(hv.y); a2 += wg*us2f(hv.z); a3 += wg*us2f(hv.w);
    }
  }
  #pragma unroll
  for(int off=1; off<64; off<<=1){
    #pragma unroll
    for(int q=0;q<4;q++) den[q] += __shfl_xor(den[q], off, 64);
  }
  float inv = 1.f/(den[h] + 1e-16f);
  int c = lane*4;
  float o[4] = {a0*inv, a1*inv, a2*inv, a3*inv};
  #pragma unroll
  for(int j=0;j<4;j++){
    float v = o[j] + b1[c+j];
    v = (v - mn1[c+j]) * rsqrtf(vr1[c+j] + 1e-5f) * g1[c+j] + be1[c+j];
    v = v > 0.f ? v : (__expf(v) - 1.f);            // ELU
    o[j] = v;
  }
  *(float4*)&h2[(size_t)node*F1 + c] = make_float4(o[0],o[1],o[2],o[3]);
}

// ---- GEMM2 (8 waves/block) + attention dots layer 2 (prescaled)
__global__ __launch_bounds__(512) void k_gemm2(const float* __restrict__ h2, const float* __restrict__ W2,
    const float* __restrict__ as2, const float* __restrict__ ad2,
    float* __restrict__ h2p, float* __restrict__ aS2, float* __restrict__ aD2){
  __shared__ float w2s[F1*NC];          // 40 KB
  __shared__ float sh2[8][F1];          // 8 KB
  for(int i=threadIdx.x; i<F1*NC; i+=512) w2s[i] = W2[i];
  int w = threadIdx.x >> 6, lane = threadIdx.x & 63;
  int node = blockIdx.x*8 + w;
  {
    float4 hv = *(const float4*)&h2[(size_t)node*F1 + lane*4];
    *(float4*)&sh2[w][lane*4] = hv;
  }
  __syncthreads();
  float acc = 0.f;
  if(lane < NC){
    #pragma unroll 8
    for(int k=0; k<F1; k++) acc += sh2[w][k] * w2s[k*NC + lane];
  }
  float av = (lane < NC) ? as2[lane] : 0.f;
  float dv = (lane < NC) ? ad2[lane] : 0.f;
  float ps = acc*av, pd = acc*dv;
  #pragma unroll
  for(int off=1; off<64; off<<=1){ ps += __shfl_xor(ps,off,64); pd += __shfl_xor(pd,off,64); }
  if(lane < NC) h2p[(size_t)node*NC + lane] = acc;
  if(lane == 0){ aS2[node] = ps*LOG2E; aD2[node] = pd*LOG2E; }
}

// ---- layer-2 aggregation -> output (f32), no max pass, LDS weights
__global__ __launch_bounds__(256) void k_agg2(const float* __restrict__ h2p,
  const float* __restrict__ aS2, const float* __restrict__ aD2,
  const int* __restrict__ rowptr, const int* __restrict__ adj,
  const float* __restrict__ b2, float* __restrict__ out){
  __shared__ float lw[4][CHUNK];
  __shared__ int   lsrc[4][CHUNK];
  int w = threadIdx.x >> 6, lane = threadIdx.x & 63;
  int node = blockIdx.x*4 + w;
  int beg = rowptr[node], end = rowptr[node+1];
  float adv = aD2[node];
  float den = 0.f, acc = 0.f;
  int total = end - beg + 1;
  for(int c0=0; c0<total; c0+=CHUNK){
    int n = min(CHUNK, total - c0);
    for(int i=lane; i<n; i+=64){
      int e = beg + c0 + i;
      int src = (e < end) ? adj[e] : node;
      float ev = aS2[src] + adv; ev = ev>0.f?ev:SLOPE*ev;
      float wg = exp2f(fminf(ev,110.f));
      lsrc[w][i] = src;
      lw[w][i] = wg;
      den += wg;
    }
    asm volatile("s_waitcnt lgkmcnt(0)" ::: "memory");
    #pragma unroll 2
    for(int i=0;i<n;i++){
      int s = lsrc[w][i];
      float wg = lw[w][i];
      if(lane < NC) acc += wg * h2p[(size_t)s*NC + lane];
    }
  }
  #pragma unroll
  for(int off=1; off<64; off<<=1) den += __shfl_xor(den, off, 64);
  if(lane < NC) out[(size_t)node*NC + lane] = acc/(den + 1e-16f) + b2[lane];
}

extern "C" void kernel_launch(void* const* d_in, const int* in_sizes, int n_in,
                              void* d_out, int out_size, void* d_ws, size_t ws_size,
                              hipStream_t stream){
  (void)in_sizes; (void)n_in; (void)out_size; (void)ws_size;
  const float* x   = (const float*)d_in[0];
  const int*   ei  = (const int*)d_in[1];
  const float* W1  = (const float*)d_in[2];
  const float* as1 = (const float*)d_in[3];
  const float* ad1 = (const float*)d_in[4];
  const float* b1  = (const float*)d_in[5];
  const float* g1  = (const float*)d_in[6];
  const float* be1 = (const float*)d_in[7];
  const float* mn1 = (const float*)d_in[8];
  const float* vr1 = (const float*)d_in[9];
  const float* W2  = (const float*)d_in[10];
  const float* as2 = (const float*)d_in[11];
  const float* ad2 = (const float*)d_in[12];
  const float* b2  = (const float*)d_in[13];

  char* ws = (char*)d_ws;
  u16*  h1b    = (u16*) (ws + 0);             // 25,600,000 (bf16 h1)
  float* h2    = (float*)(ws + 25600000);     // 51,200,000
  // xh/xl alias h2 (dead once k_gemm1 completes; h2 written later by k_agg1)
  u16*  xh     = (u16*) (ws + 25600000);      // 25,600,000
  u16*  xl     = (u16*) (ws + 51200000);      // 25,600,000
  // w1h/w1l alias h2p (dead before k_gemm2 writes h2p)
  float* h2p   = (float*)(ws + 76800000);     //  8,000,000
  u16*  w1h    = (u16*) (ws + 76800000);      //    131,072
  u16*  w1l    = (u16*) (ws + 76931072);      //    131,072
  float* aS1   = (float*)(ws + 84800000);     //    800,000
  float* aD1   = (float*)(ws + 85600000);     //    800,000
  float* aS2   = (float*)(ws + 86400000);     //    200,000
  float* aD2   = (float*)(ws + 86600000);     //    200,000
  int*  rowptr = (int*)  (ws + 86800000);     //    200,016
  int*  adj    = (int*)  (ws + 87200016);     //  6,400,000
  int*  flags  = (int*)  (ws + 93600016);     //         16
  u32*  bin    = (u32*)  (ws + 93700000);     //  7,056,000 (98*18000*4)
  int*  cnt    = (int*)  (ws + 100800000);    //        392 (98*4)
  int*  rloc   = (int*)  (ws + 100801024);    //    200,704 (98*512*4)
  int*  bsum   = (int*)  (ws + 101002240);    //        392
  int*  bbase  = (int*)  (ws + 101003264);    //        392

  hipMemsetAsync(cnt, 0, NB2*sizeof(int), stream);
  k_detect<<<1, 256, 0, stream>>>(ei, flags);
  k_prep  <<<6506, 256, 0, stream>>>(x, xh, xl, W1, w1h, w1l);
  k_bin   <<<(NE+TILE-1)/TILE, 256, 0, stream>>>(ei, flags, cnt, bin);
  k_hist  <<<NB2, 256, 0, stream>>>(cnt, bin, rloc, bsum);
  k_scanb <<<1, 64, 0, stream>>>(bsum, bbase, rowptr);
  k_fill2 <<<NB2, 256, 0, stream>>>(cnt, bin, rloc, bbase, rowptr, adj);
  k_gemm1 <<<(NN+63)/64, 256, 0, stream>>>((const short*)xh, (const short*)xl,
                                           (const short*)w1h, (const short*)w1l,
                                           as1, ad1, h1b, aS1, aD1);
  k_agg1  <<<NN/4, 256, 0, stream>>>(h1b, aS1, aD1, rowptr, adj, b1, g1, be1, mn1, vr1, h2);
  k_gemm2 <<<NN/8, 512, 0, stream>>>(h2, W2, as2, ad2, h2p, aS2, aD2);
  k_agg2  <<<NN/4, 256, 0, stream>>>(h2p, aS2, aD2, rowptr, adj, b2, (float*)d_out);
}